// Round 4
// baseline (18069.624 us; speedup 1.0000x reference)
//
#include <hip/hip_runtime.h>
#include <math.h>

typedef float2 cplx;

#define PI_F 3.14159265358979323846f
#define SQC  0.8944271909999159f   // sqrt(0.8) = sqrt(2^6 * 3!^2 / (4 * 6!))

#define GS_FOR(i, n) for (int i = blockIdx.x * blockDim.x + threadIdx.x; i < (n); i += gridDim.x * blockDim.x)

// ---------------- device helpers ----------------
__device__ __forceinline__ float ufreq(int i, int n) {
  return (float)((i < (n >> 1)) ? i : i - n) * (2.0f / (float)n);
}
// filters evaluated at UNSHIFTED frequency coords (ifftshift folded into index math)
__device__ __forceinline__ void grid_lr_ang(int i, int j, int n, float* lr, float* ang) {
  float fy = ufreq(i, n), fx = ufreq(j, n);
  float r = sqrtf(fx * fx + fy * fy);
  if (i == 0 && j == 0) r = 1.0f / (float)n;  // DC: r==0 -> 1/max(h,w)
  *lr = log2f(r);
  *ang = atan2f(fy, fx);
}
__device__ __forceinline__ float rc_hi_f(float lr, float lo, float hi) {
  float t = (lr - lo) / (hi - lo);
  t = fminf(fmaxf(t, 0.0f), 1.0f);
  return sqrtf(0.5f * (1.0f - cosf(PI_F * t)));
}
__device__ __forceinline__ float rc_lo_f(float lr, float lo, float hi) {
  float t = (lr - lo) / (hi - lo);
  t = fminf(fmaxf(t, 0.0f), 1.0f);
  return sqrtf(0.5f * (1.0f + cosf(PI_F * t)));
}
__device__ __forceinline__ float wrap_d(float ang, int b) {
  float d = ang - PI_F * (float)b * 0.25f + PI_F;
  d = d - floorf(d * (0.5f / PI_F)) * (2.0f * PI_F);
  return d - PI_F;
}
__device__ __forceinline__ float amask_c(float ang, int b) {   // complex-pyramid mask
  float d = wrap_d(ang, b);
  float c = cosf(d);
  float m = 2.0f * SQC * c * c * c;
  return (fabsf(d) < 0.5f * PI_F) ? m : 0.0f;
}
__device__ __forceinline__ float amask_r(float ang, int b) {   // real recon mask
  float d = wrap_d(ang, b);
  float c = cosf(d);
  return SQC * c * c * c;
}

__device__ __forceinline__ double wred_d(double v) {
#pragma unroll
  for (int o = 32; o > 0; o >>= 1) v += __shfl_down(v, o);
  return v;
}
__device__ __forceinline__ void atom_add_wave(double* slot, double v) {
  v = wred_d(v);
  if ((threadIdx.x & 63) == 0) atomicAdd(slot, v);
}
__device__ __forceinline__ void atomicMinF(float* a, float v) {
  if (v >= 0.0f) atomicMin((int*)a, __float_as_int(v));
  else atomicMax((unsigned int*)a, __float_as_uint(v));
}
__device__ __forceinline__ void atomicMaxF(float* a, float v) {
  if (v >= 0.0f) atomicMax((int*)a, __float_as_int(v));
  else atomicMin((unsigned int*)a, __float_as_uint(v));
}

// ---------------- FFT: one block per row, radix-2 DIT in LDS ----------------
template<int LOGN, bool INV>
__global__ __launch_bounds__(256) void fft_rows_k(cplx* __restrict__ d) {
  constexpr int N = 1 << LOGN;
  __shared__ cplx sh[N];
  __shared__ cplx tw[N / 2];
  const int tid = threadIdx.x;
  const int T = blockDim.x;
  cplx* rp = d + (size_t)blockIdx.x * N;
  for (int k = tid; k < N / 2; k += T) {
    float a = (INV ? 2.0f : -2.0f) * PI_F * (float)k / (float)N;
    float s, c;
    sincosf(a, &s, &c);
    tw[k] = make_float2(c, s);
  }
  for (int i = tid; i < N; i += T) {
    unsigned r = __brev((unsigned)i) >> (32 - LOGN);
    sh[r] = rp[i];
  }
  __syncthreads();
  for (int len = 2; len <= N; len <<= 1) {
    const int half = len >> 1;
    const int tstep = N / len;
    for (int j = tid; j < N / 2; j += T) {
      int pos = j & (half - 1);
      int base = (j - pos) << 1;
      cplx w = tw[pos * tstep];
      cplx a = sh[base + pos];
      cplx b = sh[base + pos + half];
      float tx = b.x * w.x - b.y * w.y;
      float ty = b.x * w.y + b.y * w.x;
      sh[base + pos] = make_float2(a.x + tx, a.y + ty);
      sh[base + pos + half] = make_float2(a.x - tx, a.y - ty);
    }
    __syncthreads();
  }
  const float sc = INV ? (1.0f / (float)N) : 1.0f;
  for (int i = tid; i < N; i += T) {
    cplx v = sh[i];
    rp[i] = make_float2(v.x * sc, v.y * sc);
  }
}

__global__ void transpose_k(cplx* __restrict__ out, const cplx* __restrict__ in, int N) {
  __shared__ cplx tile[32][33];
  size_t po = (size_t)blockIdx.z * N * N;
  int bx = blockIdx.x * 32, by = blockIdx.y * 32;
  int x = bx + threadIdx.x;
  for (int dy = threadIdx.y; dy < 32; dy += 8)
    tile[dy][threadIdx.x] = in[po + (size_t)(by + dy) * N + x];
  __syncthreads();
  int xo = by + threadIdx.x;
  for (int dy = threadIdx.y; dy < 32; dy += 8)
    out[po + (size_t)(bx + dy) * N + xo] = tile[threadIdx.x][dy];
}

// ---------------- pointwise / gather kernels ----------------
__global__ void r2c_k(cplx* out, const float* in, int n) {
  GS_FOR(i, n) out[i] = make_float2(in[i], 0.0f);
}
// hp written in-place over spec; lod to separate buffer
__global__ void hp_lo_split_k(cplx* hp, cplx* lod, const cplx* spec, int logN) {
  int N = 1 << logN, n = N * N;
  GS_FOR(idx, n) {
    int i = idx >> logN, j = idx & (N - 1);
    float lr, ang;
    grid_lr_ang(i, j, N, &lr, &ang);
    float h0 = rc_hi_f(lr, -1.0f, 0.0f);
    float l0 = rc_lo_f(lr, -1.0f, 0.0f);
    cplx z = spec[idx];
    hp[idx]  = make_float2(z.x * h0, z.y * h0);
    lod[idx] = make_float2(z.x * l0, z.y * l0);
  }
}
__global__ void rhp_stats_k(const cplx* src, int n, double* accAbs, double* accSq) {
  double sa = 0, sq = 0;
  GS_FOR(i, n) {
    float v = src[i].x;
    sa += fabsf(v);
    sq += (double)v * (double)v;
  }
  atom_add_wave(accAbs, sa);
  atom_add_wave(accSq, sq);
}
// out[p] = cph * lod * him * amask_c(b0+p);  cph = (-i)^3 = +i
__global__ void band_spec_k(cplx* out, const cplx* lod, int logN, int b0, int P) {
  int N = 1 << logN, n = N * N;
  GS_FOR(idx, n) {
    int i = idx >> logN, j = idx & (N - 1);
    float lr, ang;
    grid_lr_ang(i, j, N, &lr, &ang);
    float him = rc_hi_f(lr, -2.0f, -1.0f);
    cplx z = lod[idx];
    for (int p = 0; p < P; ++p) {
      float m = him * amask_c(ang, b0 + p);
      out[p * n + idx] = make_float2(-z.y * m, z.x * m);  // i*(x+iy)*m
    }
  }
}
__global__ void extract_band_k(float* realc, float* mag, const cplx* src,
                               int logPer, int P, double* acc0) {
  int n = (1 << logPer) * P;
  double s0 = 0, s1 = 0, s2 = 0, s3 = 0;
  GS_FOR(idx, n) {
    cplx z = src[idx];
    float m = sqrtf(z.x * z.x + z.y * z.y);
    realc[idx] = z.x;
    mag[idx] = m;
    int p = idx >> logPer;
    if (p == 0) s0 += m; else if (p == 1) s1 += m; else if (p == 2) s2 += m; else s3 += m;
  }
  atom_add_wave(acc0 + 0, s0);
  if (P > 1) atom_add_wave(acc0 + 1, s1);
  if (P > 2) { atom_add_wave(acc0 + 2, s2); atom_add_wave(acc0 + 3, s3); }
}
__global__ void center_k(float* buf, int logPer, int P, const double* acc0) {
  int nPer = 1 << logPer, n = nPer * P;
  double inv = 1.0 / (double)nPer;
  GS_FOR(idx, n) buf[idx] -= (float)(acc0[idx >> logPer] * inv);
}
// crop center-half of spectrum (unshifted index math), * rc_lo at child grid
__global__ void lod_down_k(cplx* child, const cplx* par, int logNc) {
  int Nc = 1 << logNc, n = Nc * Nc, Np = Nc << 1;
  GS_FOR(idx, n) {
    int i = idx >> logNc, j = idx & (Nc - 1);
    int pi = (i < (Nc >> 1)) ? i : i + Nc;
    int pj = (j < (Nc >> 1)) ? j : j + Nc;
    float lr, ang;
    grid_lr_ang(i, j, Nc, &lr, &ang);
    float l0 = rc_lo_f(lr, -1.0f, 0.0f);
    cplx z = par[pi * Np + pj];
    child[idx] = make_float2(z.x * l0, z.y * l0);
  }
}
__global__ void sum_real2_k(const cplx* src, int n, double* sumAcc) {
  double s = 0;
  GS_FOR(i, n) s += (double)src[i].x;
  atom_add_wave(sumAcc, s);
}
__global__ void center_abs2_k(const cplx* src, int n, const double* sumAcc, double* absAcc) {
  float mu = (float)(*sumAcc / (double)n);
  double s = 0;
  GS_FOR(i, n) s += fabsf(src[i].x - mu);
  atom_add_wave(absAcc, s);
}
// recon chain seed at 64: (LOD4 with DC zeroed) * lo0(64-grid)
__global__ void rs4_init_k(cplx* rs, const cplx* lod4) {
  GS_FOR(idx, 4096) {
    int i = idx >> 6, j = idx & 63;
    float lr, ang;
    grid_lr_ang(i, j, 64, &lr, &ang);
    float l0 = rc_lo_f(lr, -1.0f, 0.0f);
    cplx v = lod4[idx];
    if (idx == 0) v = make_float2(0.0f, 0.0f);
    rs[idx] = make_float2(v.x * l0, v.y * l0);
  }
}
// zero-pad embed of a spectrum into 2x grid (expand; net scale 1)
__global__ void embed_rs_k(cplx* dst, const cplx* src, int logNb, int zeroDC) {
  int Nb = 1 << logNb, Nc = Nb >> 1, q = Nc >> 1, n = Nb * Nb;
  GS_FOR(idx, n) {
    int i = idx >> logNb, j = idx & (Nb - 1);
    int ci = (i < q) ? i : ((i >= Nb - q) ? (i - Nb + Nc) : -1);
    int cj = (j < q) ? j : ((j >= Nb - q) ? (j - Nb + Nc) : -1);
    cplx v = make_float2(0.0f, 0.0f);
    if (ci >= 0 && cj >= 0) {
      v = src[ci * Nc + cj];
      if (zeroDC && ci == 0 && cj == 0) v = make_float2(0.0f, 0.0f);
    }
    dst[idx] = v;
  }
}
// rs += lo0 * sum_b 0.5*him*amr_b*( L*c1 - conj(L2)*c2 )
//   where B_b(k)=i*L*him*amc(k,b), fft(Re coeff)=(B(k)+conj(B(-k)))/2, ph=i^3=-i
__global__ void recon_accum_k(cplx* rs, const cplx* lod, int logN) {
  int N = 1 << logN, n = N * N;
  GS_FOR(idx, n) {
    int i = idx >> logN, j = idx & (N - 1);
    int ni = (N - i) & (N - 1), nj = (N - j) & (N - 1);
    float lr, ang;
    grid_lr_ang(i, j, N, &lr, &ang);
    float him = rc_hi_f(lr, -2.0f, -1.0f);
    float l0 = rc_lo_f(lr, -1.0f, 0.0f);
    cplx L = lod[idx];
    cplx L2 = lod[ni * N + nj];
    float sx = 0.0f, sy = 0.0f;
#pragma unroll
    for (int b = 0; b < 4; ++b) {
      float c1 = him * amask_c(ang, b);
      float c2 = him * amask_c(ang + PI_F, b);
      float mr = him * amask_r(ang, b);
      float gx = L.x * c1 - L2.x * c2;
      float gy = L.y * c1 + L2.y * c2;
      sx += 0.5f * mr * gx;
      sy += 0.5f * mr * gy;
    }
    cplx prev = rs[idx];
    rs[idx] = make_float2(prev.x + sx * l0, prev.y + sy * l0);
  }
}
// parents: embed(band spectrum recomputed from child LOD) into parent grid; P planes from b0
__global__ void embed_band_k(cplx* dst, const cplx* lodc, int logNb, int b0, int P) {
  int Nb = 1 << logNb, Nc = Nb >> 1, q = Nc >> 1, n = Nb * Nb;
  int tot = n * P;
  GS_FOR(idxAll, tot) {
    int p = idxAll >> (2 * logNb);
    int idx = idxAll & (n - 1);
    int i = idx >> logNb, j = idx & (Nb - 1);
    int ci = (i < q) ? i : ((i >= Nb - q) ? (i - Nb + Nc) : -1);
    int cj = (j < q) ? j : ((j >= Nb - q) ? (j - Nb + Nc) : -1);
    cplx v = make_float2(0.0f, 0.0f);
    if (ci >= 0 && cj >= 0) {
      float lr, ang;
      grid_lr_ang(ci, cj, Nc, &lr, &ang);
      float m = rc_hi_f(lr, -2.0f, -1.0f) * amask_c(ang, b0 + p);
      cplx z = lodc[ci * Nc + cj];
      v = make_float2(-z.y * m, z.x * m);   // i*z*m
    }
    dst[idxAll] = v;
  }
}
// spatial autocorrelation: 41 unique offsets (ac(-d)=ac(d)); optional skew/kurt moments
template<int ST, bool SK>
__global__ void ac_spatial_k(const float* __restrict__ x, int logN, double* acBase,
                             double* m3Slot, double* m4Slot) {
  const int N = 1 << logN;
  const int n = N * N;
  const int p = blockIdx.y;
  const float* xp = x + (((size_t)p << (2 * logN)) * ST);
  float acc[41];
#pragma unroll
  for (int q = 0; q < 41; ++q) acc[q] = 0.0f;
  float a3 = 0.0f, a4 = 0.0f;
  for (int idx = blockIdx.x * blockDim.x + threadIdx.x; idx < n; idx += gridDim.x * blockDim.x) {
    int i = idx >> logN, j = idx & (N - 1);
    float xc = xp[(size_t)idx * ST];
    if (SK) {
      float x2 = xc * xc;
      a3 += x2 * xc;
      a4 += x2 * x2;
    }
#pragma unroll
    for (int q = 0; q < 41; ++q) {
      const int di = (q < 5) ? 0 : 1 + (q - 5) / 9;
      const int dj = (q < 5) ? q : ((q - 5) % 9) - 4;
      int i2 = (i + di) & (N - 1);
      int j2 = (j + dj) & (N - 1);
      acc[q] += xc * xp[(size_t)((i2 << logN) | j2) * ST];
    }
  }
  double* slots = acBase + p * 41;
#pragma unroll
  for (int q = 0; q < 41; ++q) atom_add_wave(slots + q, (double)acc[q]);
  if (SK) {
    atom_add_wave(m3Slot, (double)a3);
    atom_add_wave(m4Slot, (double)a4);
  }
}
__global__ void img_stats1_k(const float* img, int n, double* sum, float* mm) {
  double s = 0;
  float mn = INFINITY, mx = -INFINITY;
  GS_FOR(i, n) {
    float v = img[i];
    s += (double)v;
    mn = fminf(mn, v);
    mx = fmaxf(mx, v);
  }
  atom_add_wave(sum, s);
#pragma unroll
  for (int o = 32; o > 0; o >>= 1) {
    mn = fminf(mn, __shfl_down(mn, o));
    mx = fmaxf(mx, __shfl_down(mx, o));
  }
  if ((threadIdx.x & 63) == 0) {
    atomicMinF(mm + 0, mn);
    atomicMaxF(mm + 1, mx);
  }
}
__global__ void img_stats2_k(const float* img, int n, const double* sum, double* out3) {
  double mu = *sum / (double)n;
  double s2 = 0, s3 = 0, s4 = 0;
  GS_FOR(i, n) {
    double c = (double)img[i] - mu;
    double c2 = c * c;
    s2 += c2;
    s3 += c2 * c;
    s4 += c2 * c2;
  }
  atom_add_wave(out3 + 0, s2);
  atom_add_wave(out3 + 1, s3);
  atom_add_wave(out3 + 2, s4);
}
// 4x4 gram over 4 contiguous planes (+ optional per-plane sums into slots[16..19])
__global__ void gram4_k(const float* base, int n, double* slots, int withSums) {
  double g[16];
  double s[4];
#pragma unroll
  for (int q = 0; q < 16; ++q) g[q] = 0;
#pragma unroll
  for (int q = 0; q < 4; ++q) s[q] = 0;
  GS_FOR(i, n) {
    double d0 = base[i], d1 = base[n + i], d2 = base[2 * n + i], d3 = base[3 * n + i];
    g[0] += d0 * d0; g[1] += d0 * d1; g[2]  += d0 * d2; g[3]  += d0 * d3;
    g[5] += d1 * d1; g[6] += d1 * d2; g[7]  += d1 * d3;
    g[10] += d2 * d2; g[11] += d2 * d3;
    g[15] += d3 * d3;
    if (withSums) { s[0] += d0; s[1] += d1; s[2] += d2; s[3] += d3; }
  }
  g[4] = g[1]; g[8] = g[2]; g[12] = g[3]; g[9] = g[6]; g[13] = g[7]; g[14] = g[11];
#pragma unroll
  for (int q = 0; q < 16; ++q) atom_add_wave(slots + q, g[q]);
  if (withSums) {
#pragma unroll
    for (int q = 0; q < 4; ++q) atom_add_wave(slots + 16 + q, s[q]);
  }
}
// parent = expanded child band (complex): mg, double-phase real/imag; dots vs 4 mags + 4 realcs
__global__ void parent_reduce_k(const cplx* par, const float* magS, const float* realS, int n, double* slots) {
  double d[13];
#pragma unroll
  for (int q = 0; q < 13; ++q) d[q] = 0;
  GS_FOR(i, n) {
    cplx z = par[i];
    float rt = z.x, it = z.y;
    float mg = sqrtf(rt * rt + it * it);
    float rpr = 0.0f, rpi = 0.0f;
    if (mg > 0.0f) {                 // mg*cos(2*atan2(rt,it)), mg*sin(2*atan2(rt,it))
      rpr = (it * it - rt * rt) / mg;
      rpi = 2.0f * rt * it / mg;
    }
    d[0] += (double)mg;
#pragma unroll
    for (int b = 0; b < 4; ++b) d[1 + b] += (double)magS[b * n + i] * (double)mg;
#pragma unroll
    for (int b = 0; b < 4; ++b) {
      double rv = (double)realS[b * n + i];
      d[5 + b] += rv * (double)rpr;
      d[9 + b] += rv * (double)rpi;
    }
  }
#pragma unroll
  for (int q = 0; q < 13; ++q) atom_add_wave(slots + q, d[q]);
}
// lowpass parents: X (cplx field, real part) and 4 wrap-rolled copies; dots vs realc[3] (20) + 5x5 gram (25)
__global__ void lp_parent2_k(const cplx* X, const float* realS, int logN, double* slots) {
  int N = 1 << logN, n = N * N;
  double d[45];
#pragma unroll
  for (int q = 0; q < 45; ++q) d[q] = 0;
  GS_FOR(idx, n) {
    int i = idx >> logN, j = idx & (N - 1);
    float c[5];
    c[0] = X[idx].x;
    c[1] = X[i * N + ((j - 1) & (N - 1))].x;
    c[2] = X[i * N + ((j + 1) & (N - 1))].x;
    c[3] = X[((i - 1) & (N - 1)) * N + j].x;
    c[4] = X[((i + 1) & (N - 1)) * N + j].x;
#pragma unroll
    for (int b = 0; b < 4; ++b) {
      double rv = (double)realS[b * n + idx];
#pragma unroll
      for (int k = 0; k < 5; ++k) d[b * 5 + k] += rv * (double)c[k];
    }
#pragma unroll
    for (int a = 0; a < 5; ++a)
#pragma unroll
      for (int k = 0; k < 5; ++k) d[20 + a * 5 + k] += (double)c[a] * (double)c[k];
  }
#pragma unroll
  for (int q = 0; q < 45; ++q) atom_add_wave(slots + q, d[q]);
}
__global__ void init_mm_k(float* mm) {
  if (threadIdx.x == 0) { mm[0] = INFINITY; mm[1] = -INFINITY; }
}

// ---------------- final assembly of all scalar stats ----------------
// ACC layout: 0..3 img(sum,s2,s3,s4); 4 var_hp; 8..25 mag_means; 40..44 m3[s]; 48..52 m4[s];
// 56 rlp sum; 64..143 mag grams(20/s); 144..207 real grams(16/s); 208..363 parents(13 each x12);
// 370..414 lp(45); 448..1103 acm AC (16 patches x41); 1104..1308 recon AC (5 x41)
__global__ void assemble_k(float* out, const double* acc, const float* mm) {
  const int t = threadIdx.x;
  const double NPIX = 1048576.0;
  double var0 = acc[1] / (NPIX - 1.0);
  if (t == 0) {
    double mu = acc[0] / NPIX;
    out[0] = (float)mu;
    out[1] = (float)var0;
    out[2] = (float)((acc[2] / NPIX) / pow(var0, 1.5));
    out[3] = (float)((acc[3] / NPIX) / (var0 * var0));
    out[4] = mm[0];
    out[5] = mm[1];
    out[2455] = (float)(acc[4] / NPIX);  // var_hp
  }
  for (int k = t; k < 18; k += blockDim.x) {  // mag_means
    double n;
    if (k == 0) n = NPIX;
    else if (k == 17) n = 4096.0;
    else { int s = (k - 1) >> 2; double dd = (double)(1024 >> s); n = dd * dd; }
    out[6 + k] = (float)(acc[8 + k] / n);
  }
  for (int si = t; si < 5; si += blockDim.x) {  // skew_r / kurt_r (vari = AC center)
    double dd = (si == 4) ? 64.0 : (double)(1024 >> si);
    double nn = dd * dd;
    double vari = acc[1104 + si * 41] / nn;
    bool cond = (vari / var0) > 1e-6;
    double m3 = acc[40 + si] / nn, m4 = acc[48 + si] / nn;
    out[1320 + si] = (float)(cond ? m3 / pow(vari, 1.5) : 0.0);
    out[1325 + si] = (float)(cond ? m4 / (vari * vari) : 3.0);
  }
  for (int w = t; w < 656; w += blockDim.x) {  // acm with mirror
    int patch = w / 41, q = w - patch * 41;
    int s = patch >> 2, b = patch & 3;
    double dd = (double)(1024 >> s);
    double v = acc[448 + w] / (dd * dd);
    int di = (q < 5) ? 0 : 1 + (q - 5) / 9;
    int dj = (q < 5) ? q : ((q - 5) % 9) - 4;
    int pi = 4 + di, pj = 4 + dj;
    out[24 + 144 * pi + 16 * pj + 4 * s + b] = (float)v;
    if (q) out[24 + 144 * (8 - pi) + 16 * (8 - pj) + 4 * s + b] = (float)v;
  }
  for (int w = t; w < 205; w += blockDim.x) {  // auto_corr with mirror
    int si = w / 41, q = w - si * 41;
    double dd = (si == 4) ? 64.0 : (double)(1024 >> si);
    double v = acc[1104 + w] / (dd * dd);
    int di = (q < 5) ? 0 : 1 + (q - 5) / 9;
    int dj = (q < 5) ? q : ((q - 5) % 9) - 4;
    int pi = 4 + di, pj = 4 + dj;
    out[1330 + (pi * 9 + pj) * 5 + si] = (float)v;
    if (q) out[1330 + ((8 - pi) * 9 + (8 - pj)) * 5 + si] = (float)v;
  }
  for (int q = t; q < 64; q += blockDim.x) {  // coc_mag s=0..3
    int s = q >> 4, ij = q & 15;
    double dd = (double)(1024 >> s); double csz = dd * dd;
    out[1735 + ij * 5 + s] = (float)(acc[64 + s * 20 + ij] / csz);
  }
  for (int q = t; q < 64; q += blockDim.x) {  // coc_real s=0..3 (top-left 4x4 of 8x8)
    int s = q >> 4, ij = q & 15;
    int i = ij >> 2, j = ij & 3;
    double dd = (double)(1024 >> s); double csz = dd * dd;
    out[1879 + (i * 8 + j) * 5 + s] = (float)(acc[144 + s * 16 + ij] / csz);
  }
  for (int q = t; q < 25; q += blockDim.x) {  // coc_real s=4 (5x5, /(csz/4))
    int a = q / 5, b2 = q - a * 5;
    out[1879 + (a * 8 + b2) * 5 + 4] = (float)(acc[390 + q] / 4096.0);
  }
  for (int q = t; q < 48; q += blockDim.x) {  // csc_mag s=0..2
    int s = q >> 4, ij = q & 15;
    int i = ij >> 2, pb = ij & 3;
    double dd = (double)(1024 >> s); double csz = dd * dd;
    const double* ps = acc + 208 + (s * 4 + pb) * 13;
    double meanp = ps[0] / csz;
    double cousSum = acc[64 + s * 20 + 16 + i];
    out[1815 + (i * 4 + pb) * 4 + s] = (float)((ps[1 + i] - meanp * cousSum) / csz);
  }
  for (int q = t; q < 96; q += blockDim.x) {  // csc_real s=0..2 (4x8)
    int s = q >> 5, r = q & 31;
    int i = r >> 3, j = r & 7;
    int pb = j & 3, offq = (j >= 4) ? 9 : 5;
    double dd = (double)(1024 >> s); double csz = dd * dd;
    out[2199 + (i * 8 + j) * 4 + s] = (float)(acc[208 + (s * 4 + pb) * 13 + offq + i] / csz);
  }
  for (int q = t; q < 20; q += blockDim.x) {  // csc_real s=3 (4x5)
    int i = q / 5, c = q - i * 5;
    out[2199 + (i * 8 + c) * 4 + 3] = (float)(acc[370 + q] / 16384.0);
  }
}

// ---------------- host-side helpers ----------------
static void fft_rows(cplx* d, int N, int rows, bool inv, hipStream_t st) {
  dim3 g(rows);
  int T = (N >= 512) ? 256 : ((N == 256) ? 128 : 64);
  dim3 b(T);
  switch (N) {
    case 64:   if (inv) fft_rows_k<6,  true><<<g, b, 0, st>>>(d); else fft_rows_k<6,  false><<<g, b, 0, st>>>(d); break;
    case 128:  if (inv) fft_rows_k<7,  true><<<g, b, 0, st>>>(d); else fft_rows_k<7,  false><<<g, b, 0, st>>>(d); break;
    case 256:  if (inv) fft_rows_k<8,  true><<<g, b, 0, st>>>(d); else fft_rows_k<8,  false><<<g, b, 0, st>>>(d); break;
    case 512:  if (inv) fft_rows_k<9,  true><<<g, b, 0, st>>>(d); else fft_rows_k<9,  false><<<g, b, 0, st>>>(d); break;
    case 1024: if (inv) fft_rows_k<10, true><<<g, b, 0, st>>>(d); else fft_rows_k<10, false><<<g, b, 0, st>>>(d); break;
    default: break;
  }
}
static void fft2d(cplx* a, cplx* b, int N, int P, bool inv, hipStream_t st) {
  fft_rows(a, N, N * P, inv, st);
  dim3 tg(N / 32, N / 32, P), tb(32, 8);
  transpose_k<<<tg, tb, 0, st>>>(b, a, N);
  fft_rows(b, N, N * P, inv, st);
  transpose_k<<<tg, tb, 0, st>>>(a, b, N);
}
static inline dim3 gsz(int n) {
  int b = (n + 255) >> 8;
  if (b > 2048) b = 2048;
  if (b < 1) b = 1;
  return dim3(b);
}

extern "C" void kernel_launch(void* const* d_in, const int* in_sizes, int n_in,
                              void* d_out, int out_size, void* d_ws, size_t ws_size,
                              hipStream_t stream) {
  (void)in_sizes; (void)n_in; (void)out_size; (void)ws_size;
  const float* img = (const float*)d_in[0];
  float* out = (float*)d_out;

  char* wsb = (char*)d_ws;
  size_t off = 0;
  auto alloc = [&](size_t bytes) -> void* {
    void* p = wsb + off;
    off += (bytes + 255) & ~(size_t)255;
    return p;
  };
  const size_t MB = (size_t)1 << 20;
  cplx* cA = (cplx*)alloc(16 * MB);
  cplx* cB = (cplx*)alloc(16 * MB);
  cplx* LOD[5];
  for (int s = 0; s < 5; ++s) {
    int N = 1024 >> s;
    LOD[s] = (cplx*)alloc((size_t)N * N * sizeof(cplx));
  }
  cplx* RSa = (cplx*)alloc(8 * MB);   // recon spectra s=4,2,0
  cplx* RSb = (cplx*)alloc(2 * MB);   // recon spectra s=3,1
  float* MAG[4];
  float* REALC[4];
  for (int s = 0; s < 4; ++s) {
    int N = 1024 >> s;
    MAG[s] = (float*)alloc((size_t)4 * N * N * sizeof(float));
  }
  for (int s = 0; s < 4; ++s) {
    int N = 1024 >> s;
    REALC[s] = (float*)alloc((size_t)4 * N * N * sizeof(float));
  }
  const int NPIX = 1024 * 1024;
  double* ACC = (double*)alloc(2048 * 8);
  float* MM   = (float*)alloc(256);

  hipMemsetAsync(out, 0, 2456 * sizeof(float), stream);
  hipMemsetAsync(ACC, 0, 2048 * 8, stream);
  init_mm_k<<<1, 64, 0, stream>>>(MM);

  // ---- Phase A: pixel stats ----
  img_stats1_k<<<gsz(NPIX), 256, 0, stream>>>(img, NPIX, ACC + 0, MM);
  img_stats2_k<<<gsz(NPIX), 256, 0, stream>>>(img, NPIX, ACC + 0, ACC + 1);

  // ---- Phase B: steerable pyramid ----
  r2c_k<<<gsz(NPIX), 256, 0, stream>>>(cA, img, NPIX);
  fft2d(cA, cB, 1024, 1, false, stream);
  hp_lo_split_k<<<gsz(NPIX), 256, 0, stream>>>(cA, LOD[0], cA, 10);   // hp in-place
  fft2d(cA, cB, 1024, 1, true, stream);
  rhp_stats_k<<<gsz(NPIX), 256, 0, stream>>>(cA, NPIX, ACC + 8, ACC + 4);
  for (int b0 = 0; b0 < 4; b0 += 2) {  // s=0 bands, 2-plane batches
    band_spec_k<<<gsz(NPIX), 256, 0, stream>>>(cA, LOD[0], 10, b0, 2);
    fft2d(cA, cB, 1024, 2, true, stream);
    extract_band_k<<<gsz(2 * NPIX), 256, 0, stream>>>(REALC[0] + (size_t)b0 * NPIX,
                                                      MAG[0] + (size_t)b0 * NPIX, cA, 20, 2, ACC + 9 + b0);
  }
  center_k<<<gsz(4 * NPIX), 256, 0, stream>>>(MAG[0], 20, 4, ACC + 9);
  lod_down_k<<<gsz(512 * 512), 256, 0, stream>>>(LOD[1], LOD[0], 9);
  for (int s = 1; s <= 3; ++s) {  // batched 4 bands
    int N = 1024 >> s, logN = 10 - s, n = N * N;
    band_spec_k<<<gsz(n), 256, 0, stream>>>(cA, LOD[s], logN, 0, 4);
    fft2d(cA, cB, N, 4, true, stream);
    extract_band_k<<<gsz(4 * n), 256, 0, stream>>>(REALC[s], MAG[s], cA, 2 * logN, 4, ACC + 9 + s * 4);
    center_k<<<gsz(4 * n), 256, 0, stream>>>(MAG[s], 2 * logN, 4, ACC + 9 + s * 4);
    lod_down_k<<<gsz((N / 2) * (N / 2)), 256, 0, stream>>>(LOD[s + 1], LOD[s], logN - 1);
  }
  // residual lowpass: spatial stats only (LOD[4] spectrum preserved for reuse)
  hipMemcpyAsync(cA, LOD[4], 4096 * sizeof(cplx), hipMemcpyDeviceToDevice, stream);
  fft2d(cA, cB, 64, 1, true, stream);
  sum_real2_k<<<gsz(4096), 256, 0, stream>>>(cA, 4096, ACC + 56);
  center_abs2_k<<<gsz(4096), 256, 0, stream>>>(cA, 4096, ACC + 56, ACC + 25);

  // ---- acm: spatial autocorr of centered mags (one kernel per scale) ----
  for (int s = 0; s < 4; ++s) {
    int n = (1024 >> s) * (1024 >> s);
    dim3 g(gsz(n).x, 4);
    ac_spatial_k<1, false><<<g, 256, 0, stream>>>(MAG[s], 10 - s, ACC + 448 + s * 4 * 41, nullptr, nullptr);
  }

  // ---- Phase C: recon chain in frequency domain ----
  rs4_init_k<<<gsz(4096), 256, 0, stream>>>(RSa, LOD[4]);
  hipMemcpyAsync(cA, RSa, 4096 * sizeof(cplx), hipMemcpyDeviceToDevice, stream);
  fft2d(cA, cB, 64, 1, true, stream);
  ac_spatial_k<2, true><<<dim3(gsz(4096).x, 1), 256, 0, stream>>>((const float*)cA, 6,
      ACC + 1104 + 4 * 41, ACC + 40 + 4, ACC + 48 + 4);
  cplx* cur = RSa;
  for (int s = 3; s >= 0; --s) {
    int N = 1024 >> s, logN = 10 - s, n = N * N;
    cplx* nxt = (s == 3 || s == 1) ? RSb : RSa;
    embed_rs_k<<<gsz(n), 256, 0, stream>>>(nxt, cur, logN, 0);
    recon_accum_k<<<gsz(n), 256, 0, stream>>>(nxt, LOD[s], logN);
    hipMemcpyAsync(cA, nxt, (size_t)n * sizeof(cplx), hipMemcpyDeviceToDevice, stream);
    fft2d(cA, cB, N, 1, true, stream);
    ac_spatial_k<2, true><<<dim3(gsz(n).x, 1), 256, 0, stream>>>((const float*)cA, logN,
        ACC + 1104 + s * 41, ACC + 40 + s, ACC + 48 + s);
    cur = nxt;
  }

  // ---- Phase D: cross-correlations ----
  for (int s = 0; s < 4; ++s) {
    int N = 1024 >> s, n = N * N;
    gram4_k<<<gsz(n), 256, 0, stream>>>(MAG[s], n, ACC + 64 + s * 20, 1);
    gram4_k<<<gsz(n), 256, 0, stream>>>(REALC[s], n, ACC + 144 + s * 16, 0);
  }
  // s=0 parents from LOD[1] (2-plane batches)
  for (int pb0 = 0; pb0 < 4; pb0 += 2) {
    embed_band_k<<<gsz(2 * NPIX), 256, 0, stream>>>(cA, LOD[1], 10, pb0, 2);
    fft2d(cA, cB, 1024, 2, true, stream);
    for (int p = 0; p < 2; ++p)
      parent_reduce_k<<<gsz(NPIX), 256, 0, stream>>>(cA + (size_t)p * NPIX, MAG[0], REALC[0], NPIX,
                                                     ACC + 208 + (pb0 + p) * 13);
  }
  // s=1,2 parents batched
  for (int s = 1; s <= 2; ++s) {
    int N = 1024 >> s, logN = 10 - s, n = N * N;
    embed_band_k<<<gsz(4 * n), 256, 0, stream>>>(cA, LOD[s + 1], logN, 0, 4);
    fft2d(cA, cB, N, 4, true, stream);
    for (int p = 0; p < 4; ++p)
      parent_reduce_k<<<gsz(n), 256, 0, stream>>>(cA + (size_t)p * n, MAG[s], REALC[s], n,
                                                  ACC + 208 + (s * 4 + p) * 13);
  }
  // s=3: expanded (centered) lowpass + rolls
  embed_rs_k<<<gsz(128 * 128), 256, 0, stream>>>(cA, LOD[4], 7, 1);
  fft2d(cA, cB, 128, 1, true, stream);
  lp_parent2_k<<<gsz(128 * 128), 256, 0, stream>>>(cA, REALC[3], 7, ACC + 370);

  assemble_k<<<1, 256, 0, stream>>>(out, ACC, MM);
}

// Round 5
// 1226.436 us; speedup vs baseline: 14.7334x; 14.7334x over previous
//
#include <hip/hip_runtime.h>
#include <math.h>

typedef float2 cplx;

#define PI_F 3.14159265358979323846f
#define SQC  0.8944271909999159f   // sqrt(0.8) = sqrt(2^6 * 3!^2 / (4 * 6!))

#define GS_FOR(i, n) for (int i = blockIdx.x * blockDim.x + threadIdx.x; i < (n); i += gridDim.x * blockDim.x)
#define RED_GRID 256   // all reduction producers use exactly 256 blocks (partials layout)

// ---------------- device helpers ----------------
__device__ __forceinline__ float ufreq(int i, int n) {
  return (float)((i < (n >> 1)) ? i : i - n) * (2.0f / (float)n);
}
__device__ __forceinline__ void grid_lr_ang(int i, int j, int n, float* lr, float* ang) {
  float fy = ufreq(i, n), fx = ufreq(j, n);
  float r = sqrtf(fx * fx + fy * fy);
  if (i == 0 && j == 0) r = 1.0f / (float)n;
  *lr = log2f(r);
  *ang = atan2f(fy, fx);
}
__device__ __forceinline__ float rc_hi_f(float lr, float lo, float hi) {
  float t = (lr - lo) / (hi - lo);
  t = fminf(fmaxf(t, 0.0f), 1.0f);
  return sqrtf(0.5f * (1.0f - cosf(PI_F * t)));
}
__device__ __forceinline__ float rc_lo_f(float lr, float lo, float hi) {
  float t = (lr - lo) / (hi - lo);
  t = fminf(fmaxf(t, 0.0f), 1.0f);
  return sqrtf(0.5f * (1.0f + cosf(PI_F * t)));
}
__device__ __forceinline__ float wrap_d(float ang, int b) {
  float d = ang - PI_F * (float)b * 0.25f + PI_F;
  d = d - floorf(d * (0.5f / PI_F)) * (2.0f * PI_F);
  return d - PI_F;
}
__device__ __forceinline__ float amask_c(float ang, int b) {
  float d = wrap_d(ang, b);
  float c = cosf(d);
  float m = 2.0f * SQC * c * c * c;
  return (fabsf(d) < 0.5f * PI_F) ? m : 0.0f;
}
__device__ __forceinline__ float amask_r(float ang, int b) {
  float d = wrap_d(ang, b);
  float c = cosf(d);
  return SQC * c * c * c;
}

__device__ __forceinline__ double wred_d(double v) {
#pragma unroll
  for (int o = 32; o > 0; o >>= 1) v += __shfl_down(v, o);
  return v;
}
// block partial -> PART[slot][256]; NO atomics. blockDim must be 256 (4 waves).
template<int NS>
__device__ __forceinline__ void block_to_parts(double* __restrict__ part, int slotBase, double* v) {
  __shared__ double lds[NS][4];
  const int wid = threadIdx.x >> 6, lane = threadIdx.x & 63;
#pragma unroll
  for (int q = 0; q < NS; ++q) {
    double r = wred_d(v[q]);
    if (lane == 0) lds[q][wid] = r;
  }
  __syncthreads();
  for (int q = threadIdx.x; q < NS; q += blockDim.x) {
    double s = lds[q][0] + lds[q][1] + lds[q][2] + lds[q][3];
    part[(size_t)(slotBase + q) * RED_GRID + blockIdx.x] = s;
  }
}
// finisher: ACC[base+blk] = sum of 256 partials (deterministic, idempotent)
__global__ void reduce_parts_k(double* __restrict__ acc, const double* __restrict__ part, int base) {
  const double* p = part + (size_t)(base + blockIdx.x) * RED_GRID;
  double s = 0;
  for (int i = threadIdx.x; i < RED_GRID; i += 64) s += p[i];
  s = wred_d(s);
  if (threadIdx.x == 0) acc[base + blockIdx.x] = s;
}
__device__ __forceinline__ void atomicMinF(float* a, float v) {
  if (v >= 0.0f) atomicMin((int*)a, __float_as_int(v));
  else atomicMax((unsigned int*)a, __float_as_uint(v));
}
__device__ __forceinline__ void atomicMaxF(float* a, float v) {
  if (v >= 0.0f) atomicMax((int*)a, __float_as_int(v));
  else atomicMin((unsigned int*)a, __float_as_uint(v));
}

// ---------------- FFT: one block per row, radix-2 DIT in LDS ----------------
template<int LOGN, bool INV>
__global__ __launch_bounds__(256) void fft_rows_k(cplx* __restrict__ d) {
  constexpr int N = 1 << LOGN;
  __shared__ cplx sh[N];
  __shared__ cplx tw[N / 2];
  const int tid = threadIdx.x;
  const int T = blockDim.x;
  cplx* rp = d + (size_t)blockIdx.x * N;
  for (int k = tid; k < N / 2; k += T) {
    float a = (INV ? 2.0f : -2.0f) * PI_F * (float)k / (float)N;
    float s, c;
    sincosf(a, &s, &c);
    tw[k] = make_float2(c, s);
  }
  for (int i = tid; i < N; i += T) {
    unsigned r = __brev((unsigned)i) >> (32 - LOGN);
    sh[r] = rp[i];
  }
  __syncthreads();
  for (int len = 2; len <= N; len <<= 1) {
    const int half = len >> 1;
    const int tstep = N / len;
    for (int j = tid; j < N / 2; j += T) {
      int pos = j & (half - 1);
      int base = (j - pos) << 1;
      cplx w = tw[pos * tstep];
      cplx a = sh[base + pos];
      cplx b = sh[base + pos + half];
      float tx = b.x * w.x - b.y * w.y;
      float ty = b.x * w.y + b.y * w.x;
      sh[base + pos] = make_float2(a.x + tx, a.y + ty);
      sh[base + pos + half] = make_float2(a.x - tx, a.y - ty);
    }
    __syncthreads();
  }
  const float sc = INV ? (1.0f / (float)N) : 1.0f;
  for (int i = tid; i < N; i += T) {
    cplx v = sh[i];
    rp[i] = make_float2(v.x * sc, v.y * sc);
  }
}

__global__ void transpose_k(cplx* __restrict__ out, const cplx* __restrict__ in, int N) {
  __shared__ cplx tile[32][33];
  size_t po = (size_t)blockIdx.z * N * N;
  int bx = blockIdx.x * 32, by = blockIdx.y * 32;
  int x = bx + threadIdx.x;
  for (int dy = threadIdx.y; dy < 32; dy += 8)
    tile[dy][threadIdx.x] = in[po + (size_t)(by + dy) * N + x];
  __syncthreads();
  int xo = by + threadIdx.x;
  for (int dy = threadIdx.y; dy < 32; dy += 8)
    out[po + (size_t)(bx + dy) * N + xo] = tile[threadIdx.x][dy];
}

// ---------------- pointwise / gather kernels ----------------
__global__ void r2c_k(cplx* out, const float* in, int n) {
  GS_FOR(i, n) out[i] = make_float2(in[i], 0.0f);
}
__global__ void hp_lo_split_k(cplx* hp, cplx* lod, const cplx* spec, int logN) {
  int N = 1 << logN, n = N * N;
  GS_FOR(idx, n) {
    int i = idx >> logN, j = idx & (N - 1);
    float lr, ang;
    grid_lr_ang(i, j, N, &lr, &ang);
    float h0 = rc_hi_f(lr, -1.0f, 0.0f);
    float l0 = rc_lo_f(lr, -1.0f, 0.0f);
    cplx z = spec[idx];
    hp[idx]  = make_float2(z.x * h0, z.y * h0);
    lod[idx] = make_float2(z.x * l0, z.y * l0);
  }
}
// slots 4 (sum|rhp|), 5 (sum rhp^2)
__global__ void rhp_stats_k(const cplx* src, int n, double* part) {
  double sa = 0, sq = 0;
  GS_FOR(i, n) {
    float v = src[i].x;
    sa += fabsf(v);
    sq += (double)v * (double)v;
  }
  double v[2] = {sa, sq};
  block_to_parts<2>(part, 4, v);
}
__global__ void band_spec_k(cplx* out, const cplx* lod, int logN, int b0, int P) {
  int N = 1 << logN, n = N * N;
  GS_FOR(idx, n) {
    int i = idx >> logN, j = idx & (N - 1);
    float lr, ang;
    grid_lr_ang(i, j, N, &lr, &ang);
    float him = rc_hi_f(lr, -2.0f, -1.0f);
    cplx z = lod[idx];
    for (int p = 0; p < P; ++p) {
      float m = him * amask_c(ang, b0 + p);
      out[p * n + idx] = make_float2(-z.y * m, z.x * m);  // i*(x+iy)*m
    }
  }
}
template<int P>
__global__ void extract_band_k(float* realc, float* mag, const cplx* src, int logPer,
                               double* part, int slotBase) {
  int n = (1 << logPer) * P;
  double s0 = 0, s1 = 0, s2 = 0, s3 = 0;
  GS_FOR(idx, n) {
    cplx z = src[idx];
    float m = sqrtf(z.x * z.x + z.y * z.y);
    realc[idx] = z.x;
    mag[idx] = m;
    int p = idx >> logPer;
    if (p == 0) s0 += m; else if (p == 1) s1 += m; else if (p == 2) s2 += m; else s3 += m;
  }
  double v[4] = {s0, s1, s2, s3};
  block_to_parts<P>(part, slotBase, v);
}
__global__ void center_k(float* buf, int logPer, int P, const double* acc0) {
  int nPer = 1 << logPer, n = nPer * P;
  double inv = 1.0 / (double)nPer;
  GS_FOR(idx, n) buf[idx] -= (float)(acc0[idx >> logPer] * inv);
}
__global__ void lod_down_k(cplx* child, const cplx* par, int logNc) {
  int Nc = 1 << logNc, n = Nc * Nc, Np = Nc << 1;
  GS_FOR(idx, n) {
    int i = idx >> logNc, j = idx & (Nc - 1);
    int pi = (i < (Nc >> 1)) ? i : i + Nc;
    int pj = (j < (Nc >> 1)) ? j : j + Nc;
    float lr, ang;
    grid_lr_ang(i, j, Nc, &lr, &ang);
    float l0 = rc_lo_f(lr, -1.0f, 0.0f);
    cplx z = par[pi * Np + pj];
    child[idx] = make_float2(z.x * l0, z.y * l0);
  }
}
__global__ void sum_real2_k(const cplx* src, int n, double* part) {  // slot 24
  double s = 0;
  GS_FOR(i, n) s += (double)src[i].x;
  double v[1] = {s};
  block_to_parts<1>(part, 24, v);
}
__global__ void center_abs2_k(const cplx* src, int n, const double* acc, double* part) {  // slot 25
  float mu = (float)(acc[24] / (double)n);
  double s = 0;
  GS_FOR(i, n) s += fabsf(src[i].x - mu);
  double v[1] = {s};
  block_to_parts<1>(part, 25, v);
}
__global__ void rs4_init_k(cplx* rs, const cplx* lod4) {
  GS_FOR(idx, 4096) {
    int i = idx >> 6, j = idx & 63;
    float lr, ang;
    grid_lr_ang(i, j, 64, &lr, &ang);
    float l0 = rc_lo_f(lr, -1.0f, 0.0f);
    cplx v = lod4[idx];
    if (idx == 0) v = make_float2(0.0f, 0.0f);
    rs[idx] = make_float2(v.x * l0, v.y * l0);
  }
}
__global__ void embed_rs_k(cplx* dst, const cplx* src, int logNb, int zeroDC) {
  int Nb = 1 << logNb, Nc = Nb >> 1, q = Nc >> 1, n = Nb * Nb;
  GS_FOR(idx, n) {
    int i = idx >> logNb, j = idx & (Nb - 1);
    int ci = (i < q) ? i : ((i >= Nb - q) ? (i - Nb + Nc) : -1);
    int cj = (j < q) ? j : ((j >= Nb - q) ? (j - Nb + Nc) : -1);
    cplx v = make_float2(0.0f, 0.0f);
    if (ci >= 0 && cj >= 0) {
      v = src[ci * Nc + cj];
      if (zeroDC && ci == 0 && cj == 0) v = make_float2(0.0f, 0.0f);
    }
    dst[idx] = v;
  }
}
__global__ void recon_accum_k(cplx* rs, const cplx* lod, int logN) {
  int N = 1 << logN, n = N * N;
  GS_FOR(idx, n) {
    int i = idx >> logN, j = idx & (N - 1);
    int ni = (N - i) & (N - 1), nj = (N - j) & (N - 1);
    float lr, ang;
    grid_lr_ang(i, j, N, &lr, &ang);
    float him = rc_hi_f(lr, -2.0f, -1.0f);
    float l0 = rc_lo_f(lr, -1.0f, 0.0f);
    cplx L = lod[idx];
    cplx L2 = lod[ni * N + nj];
    float sx = 0.0f, sy = 0.0f;
#pragma unroll
    for (int b = 0; b < 4; ++b) {
      float c1 = him * amask_c(ang, b);
      float c2 = him * amask_c(ang + PI_F, b);
      float mr = him * amask_r(ang, b);
      float gx = L.x * c1 - L2.x * c2;
      float gy = L.y * c1 + L2.y * c2;
      sx += 0.5f * mr * gx;
      sy += 0.5f * mr * gy;
    }
    cplx prev = rs[idx];
    rs[idx] = make_float2(prev.x + sx * l0, prev.y + sy * l0);
  }
}
__global__ void embed_band_k(cplx* dst, const cplx* lodc, int logNb, int b0, int P) {
  int Nb = 1 << logNb, Nc = Nb >> 1, q = Nc >> 1, n = Nb * Nb;
  int tot = n * P;
  GS_FOR(idxAll, tot) {
    int p = idxAll >> (2 * logNb);
    int idx = idxAll & (n - 1);
    int i = idx >> logNb, j = idx & (Nb - 1);
    int ci = (i < q) ? i : ((i >= Nb - q) ? (i - Nb + Nc) : -1);
    int cj = (j < q) ? j : ((j >= Nb - q) ? (j - Nb + Nc) : -1);
    cplx v = make_float2(0.0f, 0.0f);
    if (ci >= 0 && cj >= 0) {
      float lr, ang;
      grid_lr_ang(ci, cj, Nc, &lr, &ang);
      float m = rc_hi_f(lr, -2.0f, -1.0f) * amask_c(ang, b0 + p);
      cplx z = lodc[ci * Nc + cj];
      v = make_float2(-z.y * m, z.x * m);   // i*z*m
    }
    dst[idxAll] = v;
  }
}
// spatial autocorrelation: 41 unique offsets (+2 moment slots if SK). grid (256, P).
template<int ST, bool SK>
__global__ void ac_spatial_k(const float* __restrict__ x, int logN, double* part, int slotBase0) {
  constexpr int NS = SK ? 43 : 41;
  const int N = 1 << logN;
  const int n = N * N;
  const int p = blockIdx.y;
  const float* xp = x + (((size_t)p << (2 * logN)) * ST);
  float acc[41];
#pragma unroll
  for (int q = 0; q < 41; ++q) acc[q] = 0.0f;
  float a3 = 0.0f, a4 = 0.0f;
  for (int idx = blockIdx.x * blockDim.x + threadIdx.x; idx < n; idx += gridDim.x * blockDim.x) {
    int i = idx >> logN, j = idx & (N - 1);
    float xc = xp[(size_t)idx * ST];
    if (SK) {
      float x2 = xc * xc;
      a3 += x2 * xc;
      a4 += x2 * x2;
    }
#pragma unroll
    for (int q = 0; q < 41; ++q) {
      const int di = (q < 5) ? 0 : 1 + (q - 5) / 9;
      const int dj = (q < 5) ? q : ((q - 5) % 9) - 4;
      int i2 = (i + di) & (N - 1);
      int j2 = (j + dj) & (N - 1);
      acc[q] += xc * xp[(size_t)((i2 << logN) | j2) * ST];
    }
  }
  double v[NS];
#pragma unroll
  for (int q = 0; q < 41; ++q) v[q] = (double)acc[q];
  if (SK) { v[41] = (double)a3; v[42] = (double)a4; }
  block_to_parts<NS>(part, slotBase0 + p * NS, v);
}
__global__ void img_stats1_k(const float* img, int n, double* part, float* mm) {  // slot 0
  double s = 0;
  float mn = INFINITY, mx = -INFINITY;
  GS_FOR(i, n) {
    float v = img[i];
    s += (double)v;
    mn = fminf(mn, v);
    mx = fmaxf(mx, v);
  }
  double v[1] = {s};
  block_to_parts<1>(part, 0, v);
#pragma unroll
  for (int o = 32; o > 0; o >>= 1) {
    mn = fminf(mn, __shfl_down(mn, o));
    mx = fmaxf(mx, __shfl_down(mx, o));
  }
  if ((threadIdx.x & 63) == 0) {
    atomicMinF(mm + 0, mn);
    atomicMaxF(mm + 1, mx);
  }
}
__global__ void img_stats2_k(const float* img, int n, const double* acc, double* part) {  // slots 1..3
  double mu = acc[0] / (double)n;
  double s2 = 0, s3 = 0, s4 = 0;
  GS_FOR(i, n) {
    double c = (double)img[i] - mu;
    double c2 = c * c;
    s2 += c2;
    s3 += c2 * c;
    s4 += c2 * c2;
  }
  double v[3] = {s2, s3, s4};
  block_to_parts<3>(part, 1, v);
}
// 4x4 gram over 4 contiguous planes (+ per-plane sums if WS)
template<bool WS>
__global__ void gram4_k(const float* base, int n, double* part, int slotBase) {
  constexpr int NS = WS ? 20 : 16;
  double g[16];
  double s[4];
#pragma unroll
  for (int q = 0; q < 16; ++q) g[q] = 0;
#pragma unroll
  for (int q = 0; q < 4; ++q) s[q] = 0;
  GS_FOR(i, n) {
    double d0 = base[i], d1 = base[n + i], d2 = base[2 * n + i], d3 = base[3 * n + i];
    g[0] += d0 * d0; g[1] += d0 * d1; g[2]  += d0 * d2; g[3]  += d0 * d3;
    g[5] += d1 * d1; g[6] += d1 * d2; g[7]  += d1 * d3;
    g[10] += d2 * d2; g[11] += d2 * d3;
    g[15] += d3 * d3;
    if (WS) { s[0] += d0; s[1] += d1; s[2] += d2; s[3] += d3; }
  }
  g[4] = g[1]; g[8] = g[2]; g[12] = g[3]; g[9] = g[6]; g[13] = g[7]; g[14] = g[11];
  double v[NS];
#pragma unroll
  for (int q = 0; q < 16; ++q) v[q] = g[q];
  if (WS) {
#pragma unroll
    for (int q = 0; q < 4; ++q) v[16 + q] = s[q];
  }
  block_to_parts<NS>(part, slotBase, v);
}
__global__ void parent_reduce_k(const cplx* par, const float* magS, const float* realS, int n,
                                double* part, int slotBase) {
  double d[13];
#pragma unroll
  for (int q = 0; q < 13; ++q) d[q] = 0;
  GS_FOR(i, n) {
    cplx z = par[i];
    float rt = z.x, it = z.y;
    float mg = sqrtf(rt * rt + it * it);
    float rpr = 0.0f, rpi = 0.0f;
    if (mg > 0.0f) {
      rpr = (it * it - rt * rt) / mg;
      rpi = 2.0f * rt * it / mg;
    }
    d[0] += (double)mg;
#pragma unroll
    for (int b = 0; b < 4; ++b) d[1 + b] += (double)magS[b * n + i] * (double)mg;
#pragma unroll
    for (int b = 0; b < 4; ++b) {
      double rv = (double)realS[b * n + i];
      d[5 + b] += rv * (double)rpr;
      d[9 + b] += rv * (double)rpi;
    }
  }
  block_to_parts<13>(part, slotBase, d);
}
__global__ void lp_parent2_k(const cplx* X, const float* realS, int logN, double* part) {  // slots 370..414
  int N = 1 << logN, n = N * N;
  double d[45];
#pragma unroll
  for (int q = 0; q < 45; ++q) d[q] = 0;
  GS_FOR(idx, n) {
    int i = idx >> logN, j = idx & (N - 1);
    float c[5];
    c[0] = X[idx].x;
    c[1] = X[i * N + ((j - 1) & (N - 1))].x;
    c[2] = X[i * N + ((j + 1) & (N - 1))].x;
    c[3] = X[((i - 1) & (N - 1)) * N + j].x;
    c[4] = X[((i + 1) & (N - 1)) * N + j].x;
#pragma unroll
    for (int b = 0; b < 4; ++b) {
      double rv = (double)realS[b * n + idx];
#pragma unroll
      for (int k = 0; k < 5; ++k) d[b * 5 + k] += rv * (double)c[k];
    }
#pragma unroll
    for (int a = 0; a < 5; ++a)
#pragma unroll
      for (int k = 0; k < 5; ++k) d[20 + a * 5 + k] += (double)c[a] * (double)c[k];
  }
  block_to_parts<45>(part, 370, d);
}
__global__ void init_mm_k(float* mm) {
  if (threadIdx.x == 0) { mm[0] = INFINITY; mm[1] = -INFINITY; }
}

// ---------------- final assembly ----------------
// ACC slots: 0 img sum; 1..3 img s2,s3,s4; 4 sum|rhp|; 5 sum rhp^2; 8..23 band mag sums;
// 24 rlp sum; 25 rlp abs sum; 64+s*20 mag grams(16)+sums(4); 144+s*16 real grams;
// 208+(s*4+p)*13 parents; 370..414 lp; 448+(s*4+b)*41 acm AC; 1104+si*43 recon AC(41)+m3+m4
__global__ void assemble_k(float* out, const double* acc, const float* mm) {
  const int t = threadIdx.x;
  const double NPIX = 1048576.0;
  double var0 = acc[1] / (NPIX - 1.0);
  if (t == 0) {
    double mu = acc[0] / NPIX;
    out[0] = (float)mu;
    out[1] = (float)var0;
    out[2] = (float)((acc[2] / NPIX) / pow(var0, 1.5));
    out[3] = (float)((acc[3] / NPIX) / (var0 * var0));
    out[4] = mm[0];
    out[5] = mm[1];
    out[2455] = (float)(acc[5] / NPIX);  // var_hp
  }
  for (int k = t; k < 18; k += blockDim.x) {  // mag_means
    double n, sv;
    if (k == 0) { n = NPIX; sv = acc[4]; }
    else if (k == 17) { n = 4096.0; sv = acc[25]; }
    else { int s = (k - 1) >> 2; double dd = (double)(1024 >> s); n = dd * dd; sv = acc[7 + k]; }
    out[6 + k] = (float)(sv / n);
  }
  for (int si = t; si < 5; si += blockDim.x) {  // skew_r / kurt_r
    double dd = (si == 4) ? 64.0 : (double)(1024 >> si);
    double nn = dd * dd;
    double vari = acc[1104 + si * 43] / nn;
    bool cond = (vari / var0) > 1e-6;
    double m3 = acc[1104 + si * 43 + 41] / nn, m4 = acc[1104 + si * 43 + 42] / nn;
    out[1320 + si] = (float)(cond ? m3 / pow(vari, 1.5) : 0.0);
    out[1325 + si] = (float)(cond ? m4 / (vari * vari) : 3.0);
  }
  for (int w = t; w < 656; w += blockDim.x) {  // acm with mirror
    int patch = w / 41, q = w - patch * 41;
    int s = patch >> 2, b = patch & 3;
    double dd = (double)(1024 >> s);
    double v = acc[448 + w] / (dd * dd);
    int di = (q < 5) ? 0 : 1 + (q - 5) / 9;
    int dj = (q < 5) ? q : ((q - 5) % 9) - 4;
    int pi = 4 + di, pj = 4 + dj;
    out[24 + 144 * pi + 16 * pj + 4 * s + b] = (float)v;
    if (q) out[24 + 144 * (8 - pi) + 16 * (8 - pj) + 4 * s + b] = (float)v;
  }
  for (int w = t; w < 205; w += blockDim.x) {  // auto_corr with mirror
    int si = w / 41, q = w - si * 41;
    double dd = (si == 4) ? 64.0 : (double)(1024 >> si);
    double v = acc[1104 + si * 43 + q] / (dd * dd);
    int di = (q < 5) ? 0 : 1 + (q - 5) / 9;
    int dj = (q < 5) ? q : ((q - 5) % 9) - 4;
    int pi = 4 + di, pj = 4 + dj;
    out[1330 + (pi * 9 + pj) * 5 + si] = (float)v;
    if (q) out[1330 + ((8 - pi) * 9 + (8 - pj)) * 5 + si] = (float)v;
  }
  for (int q = t; q < 64; q += blockDim.x) {  // coc_mag
    int s = q >> 4, ij = q & 15;
    double dd = (double)(1024 >> s); double csz = dd * dd;
    out[1735 + ij * 5 + s] = (float)(acc[64 + s * 20 + ij] / csz);
  }
  for (int q = t; q < 64; q += blockDim.x) {  // coc_real s=0..3
    int s = q >> 4, ij = q & 15;
    int i = ij >> 2, j = ij & 3;
    double dd = (double)(1024 >> s); double csz = dd * dd;
    out[1879 + (i * 8 + j) * 5 + s] = (float)(acc[144 + s * 16 + ij] / csz);
  }
  for (int q = t; q < 25; q += blockDim.x) {  // coc_real s=4
    int a = q / 5, b2 = q - a * 5;
    out[1879 + (a * 8 + b2) * 5 + 4] = (float)(acc[390 + q] / 4096.0);
  }
  for (int q = t; q < 48; q += blockDim.x) {  // csc_mag s=0..2
    int s = q >> 4, ij = q & 15;
    int i = ij >> 2, pb = ij & 3;
    double dd = (double)(1024 >> s); double csz = dd * dd;
    const double* ps = acc + 208 + (s * 4 + pb) * 13;
    double meanp = ps[0] / csz;
    double cousSum = acc[64 + s * 20 + 16 + i];
    out[1815 + (i * 4 + pb) * 4 + s] = (float)((ps[1 + i] - meanp * cousSum) / csz);
  }
  for (int q = t; q < 96; q += blockDim.x) {  // csc_real s=0..2
    int s = q >> 5, r = q & 31;
    int i = r >> 3, j = r & 7;
    int pb = j & 3, offq = (j >= 4) ? 9 : 5;
    double dd = (double)(1024 >> s); double csz = dd * dd;
    out[2199 + (i * 8 + j) * 4 + s] = (float)(acc[208 + (s * 4 + pb) * 13 + offq + i] / csz);
  }
  for (int q = t; q < 20; q += blockDim.x) {  // csc_real s=3
    int i = q / 5, c = q - i * 5;
    out[2199 + (i * 8 + c) * 4 + 3] = (float)(acc[370 + q] / 16384.0);
  }
}

// ---------------- host-side helpers ----------------
static void fft_rows(cplx* d, int N, int rows, bool inv, hipStream_t st) {
  dim3 g(rows);
  int T = (N >= 512) ? 256 : ((N == 256) ? 128 : 64);
  dim3 b(T);
  switch (N) {
    case 64:   if (inv) fft_rows_k<6,  true><<<g, b, 0, st>>>(d); else fft_rows_k<6,  false><<<g, b, 0, st>>>(d); break;
    case 128:  if (inv) fft_rows_k<7,  true><<<g, b, 0, st>>>(d); else fft_rows_k<7,  false><<<g, b, 0, st>>>(d); break;
    case 256:  if (inv) fft_rows_k<8,  true><<<g, b, 0, st>>>(d); else fft_rows_k<8,  false><<<g, b, 0, st>>>(d); break;
    case 512:  if (inv) fft_rows_k<9,  true><<<g, b, 0, st>>>(d); else fft_rows_k<9,  false><<<g, b, 0, st>>>(d); break;
    case 1024: if (inv) fft_rows_k<10, true><<<g, b, 0, st>>>(d); else fft_rows_k<10, false><<<g, b, 0, st>>>(d); break;
    default: break;
  }
}
static void fft2d(cplx* a, cplx* b, int N, int P, bool inv, hipStream_t st) {
  fft_rows(a, N, N * P, inv, st);
  dim3 tg(N / 32, N / 32, P), tb(32, 8);
  transpose_k<<<tg, tb, 0, st>>>(b, a, N);
  fft_rows(b, N, N * P, inv, st);
  transpose_k<<<tg, tb, 0, st>>>(a, b, N);
}
static inline dim3 gsz(int n) {
  int b = (n + 255) >> 8;
  if (b > 2048) b = 2048;
  if (b < 1) b = 1;
  return dim3(b);
}

extern "C" void kernel_launch(void* const* d_in, const int* in_sizes, int n_in,
                              void* d_out, int out_size, void* d_ws, size_t ws_size,
                              hipStream_t stream) {
  (void)in_sizes; (void)n_in; (void)out_size; (void)ws_size;
  const float* img = (const float*)d_in[0];
  float* out = (float*)d_out;

  char* wsb = (char*)d_ws;
  size_t off = 0;
  auto alloc = [&](size_t bytes) -> void* {
    void* p = wsb + off;
    off += (bytes + 255) & ~(size_t)255;
    return p;
  };
  const size_t MB = (size_t)1 << 20;
  const int NSLOT = 1320;
  cplx* cA = (cplx*)alloc(16 * MB);
  cplx* cB = (cplx*)alloc(16 * MB);
  cplx* LOD[5];
  for (int s = 0; s < 5; ++s) {
    int N = 1024 >> s;
    LOD[s] = (cplx*)alloc((size_t)N * N * sizeof(cplx));
  }
  cplx* RS[4];  // recon spectra: seed 64^2, then 128^2, 256^2, 512^2 (s=0 goes into cA)
  for (int k = 0; k < 4; ++k) {
    int N = 64 << k;
    RS[k] = (cplx*)alloc((size_t)N * N * sizeof(cplx));
  }
  float* MAG[4];
  float* REALC[4];
  for (int s = 0; s < 4; ++s) {
    int N = 1024 >> s;
    MAG[s] = (float*)alloc((size_t)4 * N * N * sizeof(float));
  }
  for (int s = 0; s < 4; ++s) {
    int N = 1024 >> s;
    REALC[s] = (float*)alloc((size_t)4 * N * N * sizeof(float));
  }
  const int NPIX = 1024 * 1024;
  double* PART = (double*)alloc((size_t)NSLOT * RED_GRID * 8);
  double* ACC  = (double*)alloc(2048 * 8);
  float* MM    = (float*)alloc(256);

  auto finish = [&](int base, int count) {
    reduce_parts_k<<<dim3(count), 64, 0, stream>>>(ACC, PART, base);
  };

  hipMemsetAsync(out, 0, 2456 * sizeof(float), stream);
  init_mm_k<<<1, 64, 0, stream>>>(MM);

  // ---- Phase A: pixel stats ----
  img_stats1_k<<<dim3(RED_GRID), 256, 0, stream>>>(img, NPIX, PART, MM);
  finish(0, 1);
  img_stats2_k<<<dim3(RED_GRID), 256, 0, stream>>>(img, NPIX, ACC, PART);

  // ---- Phase B: steerable pyramid ----
  r2c_k<<<gsz(NPIX), 256, 0, stream>>>(cA, img, NPIX);
  fft2d(cA, cB, 1024, 1, false, stream);
  hp_lo_split_k<<<gsz(NPIX), 256, 0, stream>>>(cA, LOD[0], cA, 10);
  fft2d(cA, cB, 1024, 1, true, stream);
  rhp_stats_k<<<dim3(RED_GRID), 256, 0, stream>>>(cA, NPIX, PART);
  for (int b0 = 0; b0 < 4; b0 += 2) {  // s=0 bands, 2-plane batches
    band_spec_k<<<gsz(NPIX), 256, 0, stream>>>(cA, LOD[0], 10, b0, 2);
    fft2d(cA, cB, 1024, 2, true, stream);
    extract_band_k<2><<<dim3(RED_GRID), 256, 0, stream>>>(REALC[0] + (size_t)b0 * NPIX,
                                                          MAG[0] + (size_t)b0 * NPIX, cA, 20, PART, 8 + b0);
  }
  finish(8, 4);
  center_k<<<gsz(4 * NPIX), 256, 0, stream>>>(MAG[0], 20, 4, ACC + 8);
  lod_down_k<<<gsz(512 * 512), 256, 0, stream>>>(LOD[1], LOD[0], 9);
  for (int s = 1; s <= 3; ++s) {
    int N = 1024 >> s, logN = 10 - s, n = N * N;
    band_spec_k<<<gsz(n), 256, 0, stream>>>(cA, LOD[s], logN, 0, 4);
    fft2d(cA, cB, N, 4, true, stream);
    extract_band_k<4><<<dim3(RED_GRID), 256, 0, stream>>>(REALC[s], MAG[s], cA, 2 * logN, PART, 8 + 4 * s);
    finish(8 + 4 * s, 4);
    center_k<<<gsz(4 * n), 256, 0, stream>>>(MAG[s], 2 * logN, 4, ACC + 8 + 4 * s);
    lod_down_k<<<gsz((N / 2) * (N / 2)), 256, 0, stream>>>(LOD[s + 1], LOD[s], logN - 1);
  }
  // residual lowpass spatial stats (LOD[4] spectrum preserved)
  hipMemcpyAsync(cA, LOD[4], 4096 * sizeof(cplx), hipMemcpyDeviceToDevice, stream);
  fft2d(cA, cB, 64, 1, true, stream);
  sum_real2_k<<<dim3(RED_GRID), 256, 0, stream>>>(cA, 4096, PART);
  finish(24, 1);
  center_abs2_k<<<dim3(RED_GRID), 256, 0, stream>>>(cA, 4096, ACC, PART);

  // ---- acm: spatial autocorr of centered mags ----
  for (int s = 0; s < 4; ++s) {
    dim3 g(RED_GRID, 4);
    ac_spatial_k<1, false><<<g, 256, 0, stream>>>(MAG[s], 10 - s, PART, 448 + s * 4 * 41);
  }

  // ---- Phase C: recon chain in frequency domain ----
  rs4_init_k<<<gsz(4096), 256, 0, stream>>>(RS[0], LOD[4]);
  hipMemcpyAsync(cA, RS[0], 4096 * sizeof(cplx), hipMemcpyDeviceToDevice, stream);
  fft2d(cA, cB, 64, 1, true, stream);
  ac_spatial_k<2, true><<<dim3(RED_GRID, 1), 256, 0, stream>>>((const float*)cA, 6, PART, 1104 + 4 * 43);
  cplx* cur = RS[0];
  for (int s = 3; s >= 0; --s) {
    int N = 1024 >> s, logN = 10 - s, n = N * N;
    cplx* nxt = (s > 0) ? RS[4 - s] : cA;
    embed_rs_k<<<gsz(n), 256, 0, stream>>>(nxt, cur, logN, 0);
    recon_accum_k<<<gsz(n), 256, 0, stream>>>(nxt, LOD[s], logN);
    if (s > 0) {
      hipMemcpyAsync(cA, nxt, (size_t)n * sizeof(cplx), hipMemcpyDeviceToDevice, stream);
    }
    fft2d(cA, cB, N, 1, true, stream);
    ac_spatial_k<2, true><<<dim3(RED_GRID, 1), 256, 0, stream>>>((const float*)cA, logN, PART, 1104 + s * 43);
    cur = nxt;
  }

  // ---- Phase D: cross-correlations ----
  for (int s = 0; s < 4; ++s) {
    int n = (1024 >> s) * (1024 >> s);
    gram4_k<true><<<dim3(RED_GRID), 256, 0, stream>>>(MAG[s], n, PART, 64 + s * 20);
    gram4_k<false><<<dim3(RED_GRID), 256, 0, stream>>>(REALC[s], n, PART, 144 + s * 16);
  }
  // s=0 parents from LOD[1] (2-plane batches)
  for (int pb0 = 0; pb0 < 4; pb0 += 2) {
    embed_band_k<<<gsz(2 * NPIX), 256, 0, stream>>>(cA, LOD[1], 10, pb0, 2);
    fft2d(cA, cB, 1024, 2, true, stream);
    for (int p = 0; p < 2; ++p)
      parent_reduce_k<<<dim3(RED_GRID), 256, 0, stream>>>(cA + (size_t)p * NPIX, MAG[0], REALC[0], NPIX,
                                                          PART, 208 + (pb0 + p) * 13);
  }
  // s=1,2 parents batched
  for (int s = 1; s <= 2; ++s) {
    int N = 1024 >> s, logN = 10 - s, n = N * N;
    embed_band_k<<<gsz(4 * n), 256, 0, stream>>>(cA, LOD[s + 1], logN, 0, 4);
    fft2d(cA, cB, N, 4, true, stream);
    for (int p = 0; p < 4; ++p)
      parent_reduce_k<<<dim3(RED_GRID), 256, 0, stream>>>(cA + (size_t)p * n, MAG[s], REALC[s], n,
                                                          PART, 208 + (s * 4 + p) * 13);
  }
  // s=3: expanded (centered) lowpass + rolls
  embed_rs_k<<<gsz(128 * 128), 256, 0, stream>>>(cA, LOD[4], 7, 1);
  fft2d(cA, cB, 128, 1, true, stream);
  lp_parent2_k<<<dim3(RED_GRID), 256, 0, stream>>>(cA, REALC[3], 7, PART);

  finish(0, NSLOT);
  assemble_k<<<1, 256, 0, stream>>>(out, ACC, MM);
}

// Round 7
// 1216.486 us; speedup vs baseline: 14.8540x; 1.0082x over previous
//
#include <hip/hip_runtime.h>
#include <math.h>

typedef float2 cplx;

#define PI_F 3.14159265358979323846f
#define SQC  0.8944271909999159f   // sqrt(0.8) = sqrt(2^6 * 3!^2 / (4 * 6!))

#define GS_FOR(i, n) for (int i = blockIdx.x * blockDim.x + threadIdx.x; i < (n); i += gridDim.x * blockDim.x)
#define RED_GRID 256   // all reduction producers use exactly 256 blocks (partials layout)

// ---------------- device helpers ----------------
__device__ __forceinline__ float ufreq(int i, int n) {
  return (float)((i < (n >> 1)) ? i : i - n) * (2.0f / (float)n);
}
__device__ __forceinline__ void grid_lr_ang(int i, int j, int n, float* lr, float* ang) {
  float fy = ufreq(i, n), fx = ufreq(j, n);
  float r = sqrtf(fx * fx + fy * fy);
  if (i == 0 && j == 0) r = 1.0f / (float)n;
  *lr = log2f(r);
  *ang = atan2f(fy, fx);
}
__device__ __forceinline__ float rc_hi_f(float lr, float lo, float hi) {
  float t = (lr - lo) / (hi - lo);
  t = fminf(fmaxf(t, 0.0f), 1.0f);
  return sqrtf(0.5f * (1.0f - cosf(PI_F * t)));
}
__device__ __forceinline__ float rc_lo_f(float lr, float lo, float hi) {
  float t = (lr - lo) / (hi - lo);
  t = fminf(fmaxf(t, 0.0f), 1.0f);
  return sqrtf(0.5f * (1.0f + cosf(PI_F * t)));
}
__device__ __forceinline__ float wrap_d(float ang, int b) {
  float d = ang - PI_F * (float)b * 0.25f + PI_F;
  d = d - floorf(d * (0.5f / PI_F)) * (2.0f * PI_F);
  return d - PI_F;
}
__device__ __forceinline__ float amask_c(float ang, int b) {
  float d = wrap_d(ang, b);
  float c = cosf(d);
  float m = 2.0f * SQC * c * c * c;
  return (fabsf(d) < 0.5f * PI_F) ? m : 0.0f;
}
__device__ __forceinline__ float amask_r(float ang, int b) {
  float d = wrap_d(ang, b);
  float c = cosf(d);
  return SQC * c * c * c;
}

__device__ __forceinline__ double wred_d(double v) {
#pragma unroll
  for (int o = 32; o > 0; o >>= 1) v += __shfl_down(v, o);
  return v;
}
// block partial -> PART[slot][256]; NO atomics. blockDim must be 256 (4 waves).
template<int NS>
__device__ __forceinline__ void block_to_parts(double* __restrict__ part, int slotBase, double* v) {
  __shared__ double lds[NS][4];
  const int wid = threadIdx.x >> 6, lane = threadIdx.x & 63;
#pragma unroll
  for (int q = 0; q < NS; ++q) {
    double r = wred_d(v[q]);
    if (lane == 0) lds[q][wid] = r;
  }
  __syncthreads();
  for (int q = threadIdx.x; q < NS; q += blockDim.x) {
    double s = lds[q][0] + lds[q][1] + lds[q][2] + lds[q][3];
    part[(size_t)(slotBase + q) * RED_GRID + blockIdx.x] = s;
  }
}
// finisher: ACC[base+blk] = sum of 256 partials (deterministic, idempotent)
__global__ void reduce_parts_k(double* __restrict__ acc, const double* __restrict__ part, int base) {
  const double* p = part + (size_t)(base + blockIdx.x) * RED_GRID;
  double s = 0;
  for (int i = threadIdx.x; i < RED_GRID; i += 64) s += p[i];
  s = wred_d(s);
  if (threadIdx.x == 0) acc[base + blockIdx.x] = s;
}
__device__ __forceinline__ void atomicMinF(float* a, float v) {
  if (v >= 0.0f) atomicMin((int*)a, __float_as_int(v));
  else atomicMax((unsigned int*)a, __float_as_uint(v));
}
__device__ __forceinline__ void atomicMaxF(float* a, float v) {
  if (v >= 0.0f) atomicMax((int*)a, __float_as_int(v));
  else atomicMin((unsigned int*)a, __float_as_uint(v));
}

// ---------------- FFT: one block per row, radix-2 DIT in LDS ----------------
template<int LOGN, bool INV>
__global__ __launch_bounds__(256) void fft_rows_k(cplx* __restrict__ d) {
  constexpr int N = 1 << LOGN;
  __shared__ cplx sh[N];
  __shared__ cplx tw[N / 2];
  const int tid = threadIdx.x;
  const int T = blockDim.x;
  cplx* rp = d + (size_t)blockIdx.x * N;
  for (int k = tid; k < N / 2; k += T) {
    float a = (INV ? 2.0f : -2.0f) * PI_F * (float)k / (float)N;
    float s, c;
    sincosf(a, &s, &c);
    tw[k] = make_float2(c, s);
  }
  for (int i = tid; i < N; i += T) {
    unsigned r = __brev((unsigned)i) >> (32 - LOGN);
    sh[r] = rp[i];
  }
  __syncthreads();
  for (int len = 2; len <= N; len <<= 1) {
    const int half = len >> 1;
    const int tstep = N / len;
    for (int j = tid; j < N / 2; j += T) {
      int pos = j & (half - 1);
      int base = (j - pos) << 1;
      cplx w = tw[pos * tstep];
      cplx a = sh[base + pos];
      cplx b = sh[base + pos + half];
      float tx = b.x * w.x - b.y * w.y;
      float ty = b.x * w.y + b.y * w.x;
      sh[base + pos] = make_float2(a.x + tx, a.y + ty);
      sh[base + pos + half] = make_float2(a.x - tx, a.y - ty);
    }
    __syncthreads();
  }
  const float sc = INV ? (1.0f / (float)N) : 1.0f;
  for (int i = tid; i < N; i += T) {
    cplx v = sh[i];
    rp[i] = make_float2(v.x * sc, v.y * sc);
  }
}

__global__ void transpose_k(cplx* __restrict__ out, const cplx* __restrict__ in, int N) {
  __shared__ cplx tile[32][33];
  size_t po = (size_t)blockIdx.z * N * N;
  int bx = blockIdx.x * 32, by = blockIdx.y * 32;
  int x = bx + threadIdx.x;
  for (int dy = threadIdx.y; dy < 32; dy += 8)
    tile[dy][threadIdx.x] = in[po + (size_t)(by + dy) * N + x];
  __syncthreads();
  int xo = by + threadIdx.x;
  for (int dy = threadIdx.y; dy < 32; dy += 8)
    out[po + (size_t)(bx + dy) * N + xo] = tile[threadIdx.x][dy];
}

// ---------------- pointwise / gather kernels ----------------
__global__ void r2c_k(cplx* out, const float* in, int n) {
  GS_FOR(i, n) out[i] = make_float2(in[i], 0.0f);
}
__global__ void hp_lo_split_k(cplx* hp, cplx* lod, const cplx* spec, int logN) {
  int N = 1 << logN, n = N * N;
  GS_FOR(idx, n) {
    int i = idx >> logN, j = idx & (N - 1);
    float lr, ang;
    grid_lr_ang(i, j, N, &lr, &ang);
    float h0 = rc_hi_f(lr, -1.0f, 0.0f);
    float l0 = rc_lo_f(lr, -1.0f, 0.0f);
    cplx z = spec[idx];
    hp[idx]  = make_float2(z.x * h0, z.y * h0);
    lod[idx] = make_float2(z.x * l0, z.y * l0);
  }
}
// slots 4 (sum|rhp|), 5 (sum rhp^2)
__global__ void rhp_stats_k(const cplx* src, int n, double* part) {
  double sa = 0, sq = 0;
  GS_FOR(i, n) {
    float v = src[i].x;
    sa += fabsf(v);
    sq += (double)v * (double)v;
  }
  double v[2] = {sa, sq};
  block_to_parts<2>(part, 4, v);
}
__global__ void band_spec_k(cplx* out, const cplx* lod, int logN, int b0, int P) {
  int N = 1 << logN, n = N * N;
  GS_FOR(idx, n) {
    int i = idx >> logN, j = idx & (N - 1);
    float lr, ang;
    grid_lr_ang(i, j, N, &lr, &ang);
    float him = rc_hi_f(lr, -2.0f, -1.0f);
    cplx z = lod[idx];
    for (int p = 0; p < P; ++p) {
      float m = him * amask_c(ang, b0 + p);
      out[p * n + idx] = make_float2(-z.y * m, z.x * m);  // i*(x+iy)*m
    }
  }
}
template<int P>
__global__ void extract_band_k(float* realc, float* mag, const cplx* src, int logPer,
                               double* part, int slotBase) {
  int n = (1 << logPer) * P;
  double s0 = 0, s1 = 0, s2 = 0, s3 = 0;
  GS_FOR(idx, n) {
    cplx z = src[idx];
    float m = sqrtf(z.x * z.x + z.y * z.y);
    realc[idx] = z.x;
    mag[idx] = m;
    int p = idx >> logPer;
    if (p == 0) s0 += m; else if (p == 1) s1 += m; else if (p == 2) s2 += m; else s3 += m;
  }
  double v[4] = {s0, s1, s2, s3};
  block_to_parts<P>(part, slotBase, v);
}
__global__ void center_k(float* buf, int logPer, int P, const double* acc0) {
  int nPer = 1 << logPer, n = nPer * P;
  double inv = 1.0 / (double)nPer;
  GS_FOR(idx, n) buf[idx] -= (float)(acc0[idx >> logPer] * inv);
}
__global__ void lod_down_k(cplx* child, const cplx* par, int logNc) {
  int Nc = 1 << logNc, n = Nc * Nc, Np = Nc << 1;
  GS_FOR(idx, n) {
    int i = idx >> logNc, j = idx & (Nc - 1);
    int pi = (i < (Nc >> 1)) ? i : i + Nc;
    int pj = (j < (Nc >> 1)) ? j : j + Nc;
    float lr, ang;
    grid_lr_ang(i, j, Nc, &lr, &ang);
    float l0 = rc_lo_f(lr, -1.0f, 0.0f);
    cplx z = par[pi * Np + pj];
    child[idx] = make_float2(z.x * l0, z.y * l0);
  }
}
__global__ void sum_real2_k(const cplx* src, int n, double* part) {  // slot 24
  double s = 0;
  GS_FOR(i, n) s += (double)src[i].x;
  double v[1] = {s};
  block_to_parts<1>(part, 24, v);
}
__global__ void center_abs2_k(const cplx* src, int n, const double* acc, double* part) {  // slot 25
  float mu = (float)(acc[24] / (double)n);
  double s = 0;
  GS_FOR(i, n) s += fabsf(src[i].x - mu);
  double v[1] = {s};
  block_to_parts<1>(part, 25, v);
}
__global__ void rs4_init_k(cplx* rs, const cplx* lod4) {
  GS_FOR(idx, 4096) {
    int i = idx >> 6, j = idx & 63;
    float lr, ang;
    grid_lr_ang(i, j, 64, &lr, &ang);
    float l0 = rc_lo_f(lr, -1.0f, 0.0f);
    cplx v = lod4[idx];
    if (idx == 0) v = make_float2(0.0f, 0.0f);
    rs[idx] = make_float2(v.x * l0, v.y * l0);
  }
}
__global__ void embed_rs_k(cplx* dst, const cplx* src, int logNb, int zeroDC) {
  int Nb = 1 << logNb, Nc = Nb >> 1, q = Nc >> 1, n = Nb * Nb;
  GS_FOR(idx, n) {
    int i = idx >> logNb, j = idx & (Nb - 1);
    int ci = (i < q) ? i : ((i >= Nb - q) ? (i - Nb + Nc) : -1);
    int cj = (j < q) ? j : ((j >= Nb - q) ? (j - Nb + Nc) : -1);
    cplx v = make_float2(0.0f, 0.0f);
    if (ci >= 0 && cj >= 0) {
      v = src[ci * Nc + cj];
      if (zeroDC && ci == 0 && cj == 0) v = make_float2(0.0f, 0.0f);
    }
    dst[idx] = v;
  }
}
// fused: dst = embed(src into 2x grid) + recon-band spectrum from lod (all at Nb grid)
__global__ void recon_step_k(cplx* __restrict__ dst, const cplx* __restrict__ src,
                             const cplx* __restrict__ lod, int logNb) {
  int Nb = 1 << logNb, Nc = Nb >> 1, qq = Nc >> 1, n = Nb * Nb;
  GS_FOR(idx, n) {
    int i = idx >> logNb, j = idx & (Nb - 1);
    int ci = (i < qq) ? i : ((i >= Nb - qq) ? (i - Nb + Nc) : -1);
    int cj = (j < qq) ? j : ((j >= Nb - qq) ? (j - Nb + Nc) : -1);
    float ex = 0.0f, ey = 0.0f;
    if (ci >= 0 && cj >= 0) { cplx v = src[ci * Nc + cj]; ex = v.x; ey = v.y; }
    int ni = (Nb - i) & (Nb - 1), nj = (Nb - j) & (Nb - 1);
    float lr, ang;
    grid_lr_ang(i, j, Nb, &lr, &ang);
    float him = rc_hi_f(lr, -2.0f, -1.0f);
    float l0 = rc_lo_f(lr, -1.0f, 0.0f);
    cplx L = lod[idx];
    cplx L2 = lod[ni * Nb + nj];
    float sx = 0.0f, sy = 0.0f;
#pragma unroll
    for (int b = 0; b < 4; ++b) {
      float c1 = him * amask_c(ang, b);
      float c2 = him * amask_c(ang + PI_F, b);
      float mr = him * amask_r(ang, b);
      float gx = L.x * c1 - L2.x * c2;
      float gy = L.y * c1 + L2.y * c2;
      sx += 0.5f * mr * gx;
      sy += 0.5f * mr * gy;
    }
    dst[idx] = make_float2(ex + sx * l0, ey + sy * l0);
  }
}
__global__ void embed_band_k(cplx* dst, const cplx* lodc, int logNb, int b0, int P) {
  int Nb = 1 << logNb, Nc = Nb >> 1, q = Nc >> 1, n = Nb * Nb;
  int tot = n * P;
  GS_FOR(idxAll, tot) {
    int p = idxAll >> (2 * logNb);
    int idx = idxAll & (n - 1);
    int i = idx >> logNb, j = idx & (Nb - 1);
    int ci = (i < q) ? i : ((i >= Nb - q) ? (i - Nb + Nc) : -1);
    int cj = (j < q) ? j : ((j >= Nb - q) ? (j - Nb + Nc) : -1);
    cplx v = make_float2(0.0f, 0.0f);
    if (ci >= 0 && cj >= 0) {
      float lr, ang;
      grid_lr_ang(ci, cj, Nc, &lr, &ang);
      float m = rc_hi_f(lr, -2.0f, -1.0f) * amask_c(ang, b0 + p);
      cplx z = lodc[ci * Nc + cj];
      v = make_float2(-z.y * m, z.x * m);   // i*z*m
    }
    dst[idxAll] = v;
  }
}
// ---- vectorized spatial autocorrelation core ----
// Each unit = 8 consecutive pixels; loads rows di=0..4, cols j0-4..j0+11 as float4s
// into a statically-indexed register file, then 8x41 FMA. ST=1: float planes; ST=2: cplx .x.
template<int ST, bool SK>
__device__ __forceinline__ void ac_core(const float* __restrict__ xp, int logN,
                                        double* __restrict__ part, int slotBase) {
  const int N = 1 << logN;
  const int nu = (N * N) >> 3;
  float acc[41];
#pragma unroll
  for (int q = 0; q < 41; ++q) acc[q] = 0.0f;
  float a3 = 0.0f, a4 = 0.0f;
  for (int u = blockIdx.x * blockDim.x + threadIdx.x; u < nu; u += gridDim.x * blockDim.x) {
    int i = u >> (logN - 3);
    int j0 = (u & ((N >> 3) - 1)) << 3;
    float buf[5][16];
#pragma unroll
    for (int di = 0; di < 5; ++di) {
      int r = ((i + di) & (N - 1)) << logN;
#pragma unroll
      for (int blk = 0; blk < 4; ++blk) {
        int c = (j0 - 4 + blk * 4) & (N - 1);   // 4-aligned, never straddles wrap
        if (ST == 1) {
          const float4 v = *reinterpret_cast<const float4*>(xp + r + c);
          buf[di][blk * 4 + 0] = v.x; buf[di][blk * 4 + 1] = v.y;
          buf[di][blk * 4 + 2] = v.z; buf[di][blk * 4 + 3] = v.w;
        } else {
          const float4 v0 = *reinterpret_cast<const float4*>(xp + ((size_t)(r + c) << 1));
          const float4 v1 = *reinterpret_cast<const float4*>(xp + ((size_t)(r + c) << 1) + 4);
          buf[di][blk * 4 + 0] = v0.x; buf[di][blk * 4 + 1] = v0.z;
          buf[di][blk * 4 + 2] = v1.x; buf[di][blk * 4 + 3] = v1.z;
        }
      }
    }
#pragma unroll
    for (int k = 0; k < 8; ++k) {
      float xc = buf[0][4 + k];
      if (SK) {
        float x2 = xc * xc;
        a3 += x2 * xc;
        a4 += x2 * x2;
      }
#pragma unroll
      for (int q = 0; q < 41; ++q) {
        const int di = (q < 5) ? 0 : 1 + (q - 5) / 9;
        const int dj = (q < 5) ? q : ((q - 5) % 9) - 4;
        acc[q] += xc * buf[di][4 + k + dj];
      }
    }
  }
  constexpr int NS = SK ? 43 : 41;
  double v[NS];
#pragma unroll
  for (int q = 0; q < 41; ++q) v[q] = (double)acc[q];
  if (SK) { v[41] = (double)a3; v[42] = (double)a4; }
  block_to_parts<NS>(part, slotBase, v);
}
// all 16 acm autocorrs in one launch: grid (256, 4 planes, 4 scales)
__global__ __launch_bounds__(256) void acm_vec_k(const float* m0, const float* m1,
                                                 const float* m2, const float* m3, double* part) {
  const int s = blockIdx.z;
  const float* base = (s == 0) ? m0 : ((s == 1) ? m1 : ((s == 2) ? m2 : m3));
  const int logN = 10 - s;
  const float* xp = base + ((size_t)blockIdx.y << (2 * logN));
  ac_core<1, false>(xp, logN, part, 448 + (s * 4 + blockIdx.y) * 41);
}
// recon-chain autocorr + skew/kurt moments (cplx input, real part)
__global__ __launch_bounds__(256) void ac_rec_k(const float* x, int logN, double* part, int slotBase) {
  ac_core<2, true>(x, logN, part, slotBase);
}
__global__ void img_stats1_k(const float* img, int n, double* part, float* mm) {  // slot 0
  double s = 0;
  float mn = INFINITY, mx = -INFINITY;
  GS_FOR(i, n) {
    float v = img[i];
    s += (double)v;
    mn = fminf(mn, v);
    mx = fmaxf(mx, v);
  }
  double v[1] = {s};
  block_to_parts<1>(part, 0, v);
#pragma unroll
  for (int o = 32; o > 0; o >>= 1) {
    mn = fminf(mn, __shfl_down(mn, o));
    mx = fmaxf(mx, __shfl_down(mx, o));
  }
  if ((threadIdx.x & 63) == 0) {
    atomicMinF(mm + 0, mn);
    atomicMaxF(mm + 1, mx);
  }
}
__global__ void img_stats2_k(const float* img, int n, const double* acc, double* part) {  // slots 1..3
  double mu = acc[0] / (double)n;
  double s2 = 0, s3 = 0, s4 = 0;
  GS_FOR(i, n) {
    double c = (double)img[i] - mu;
    double c2 = c * c;
    s2 += c2;
    s3 += c2 * c;
    s4 += c2 * c2;
  }
  double v[3] = {s2, s3, s4};
  block_to_parts<3>(part, 1, v);
}
// 4x4 gram over 4 contiguous planes (+ per-plane sums if WS)
template<bool WS>
__global__ void gram4_k(const float* base, int n, double* part, int slotBase) {
  constexpr int NS = WS ? 20 : 16;
  double g[16];
  double s[4];
#pragma unroll
  for (int q = 0; q < 16; ++q) g[q] = 0;
#pragma unroll
  for (int q = 0; q < 4; ++q) s[q] = 0;
  GS_FOR(i, n) {
    double d0 = base[i], d1 = base[n + i], d2 = base[2 * n + i], d3 = base[3 * n + i];
    g[0] += d0 * d0; g[1] += d0 * d1; g[2]  += d0 * d2; g[3]  += d0 * d3;
    g[5] += d1 * d1; g[6] += d1 * d2; g[7]  += d1 * d3;
    g[10] += d2 * d2; g[11] += d2 * d3;
    g[15] += d3 * d3;
    if (WS) { s[0] += d0; s[1] += d1; s[2] += d2; s[3] += d3; }
  }
  g[4] = g[1]; g[8] = g[2]; g[12] = g[3]; g[9] = g[6]; g[13] = g[7]; g[14] = g[11];
  double v[NS];
#pragma unroll
  for (int q = 0; q < 16; ++q) v[q] = g[q];
  if (WS) {
#pragma unroll
    for (int q = 0; q < 4; ++q) v[16 + q] = s[q];
  }
  block_to_parts<NS>(part, slotBase, v);
}
__global__ void parent_reduce_k(const cplx* par, const float* magS, const float* realS, int n,
                                double* part, int slotBase) {
  double d[13];
#pragma unroll
  for (int q = 0; q < 13; ++q) d[q] = 0;
  GS_FOR(i, n) {
    cplx z = par[i];
    float rt = z.x, it = z.y;
    float mg = sqrtf(rt * rt + it * it);
    float rpr = 0.0f, rpi = 0.0f;
    if (mg > 0.0f) {
      rpr = (it * it - rt * rt) / mg;
      rpi = 2.0f * rt * it / mg;
    }
    d[0] += (double)mg;
#pragma unroll
    for (int b = 0; b < 4; ++b) d[1 + b] += (double)magS[b * n + i] * (double)mg;
#pragma unroll
    for (int b = 0; b < 4; ++b) {
      double rv = (double)realS[b * n + i];
      d[5 + b] += rv * (double)rpr;
      d[9 + b] += rv * (double)rpi;
    }
  }
  block_to_parts<13>(part, slotBase, d);
}
__global__ void lp_parent2_k(const cplx* X, const float* realS, int logN, double* part) {  // slots 370..414
  int N = 1 << logN, n = N * N;
  double d[45];
#pragma unroll
  for (int q = 0; q < 45; ++q) d[q] = 0;
  GS_FOR(idx, n) {
    int i = idx >> logN, j = idx & (N - 1);
    float c[5];
    c[0] = X[idx].x;
    c[1] = X[i * N + ((j - 1) & (N - 1))].x;
    c[2] = X[i * N + ((j + 1) & (N - 1))].x;
    c[3] = X[((i - 1) & (N - 1)) * N + j].x;
    c[4] = X[((i + 1) & (N - 1)) * N + j].x;
#pragma unroll
    for (int b = 0; b < 4; ++b) {
      double rv = (double)realS[b * n + idx];
#pragma unroll
      for (int k = 0; k < 5; ++k) d[b * 5 + k] += rv * (double)c[k];
    }
#pragma unroll
    for (int a = 0; a < 5; ++a)
#pragma unroll
      for (int k = 0; k < 5; ++k) d[20 + a * 5 + k] += (double)c[a] * (double)c[k];
  }
  block_to_parts<45>(part, 370, d);
}
__global__ void init_mm_k(float* mm) {
  if (threadIdx.x == 0) { mm[0] = INFINITY; mm[1] = -INFINITY; }
}

// ---------------- final assembly ----------------
// ACC slots: 0 img sum; 1..3 img s2,s3,s4; 4 sum|rhp|; 5 sum rhp^2; 8..23 band mag sums;
// 24 rlp sum; 25 rlp abs sum; 64+s*20 mag grams(16)+sums(4); 144+s*16 real grams;
// 208+(s*4+p)*13 parents; 370..414 lp; 448+(s*4+b)*41 acm AC; 1104+si*43 recon AC(41)+m3+m4
__global__ void assemble_k(float* out, const double* acc, const float* mm) {
  const int t = threadIdx.x;
  const double NPIX = 1048576.0;
  double var0 = acc[1] / (NPIX - 1.0);
  if (t == 0) {
    double mu = acc[0] / NPIX;
    out[0] = (float)mu;
    out[1] = (float)var0;
    out[2] = (float)((acc[2] / NPIX) / pow(var0, 1.5));
    out[3] = (float)((acc[3] / NPIX) / (var0 * var0));
    out[4] = mm[0];
    out[5] = mm[1];
    out[2455] = (float)(acc[5] / NPIX);  // var_hp
  }
  for (int k = t; k < 18; k += blockDim.x) {  // mag_means
    double n, sv;
    if (k == 0) { n = NPIX; sv = acc[4]; }
    else if (k == 17) { n = 4096.0; sv = acc[25]; }
    else { int s = (k - 1) >> 2; double dd = (double)(1024 >> s); n = dd * dd; sv = acc[7 + k]; }
    out[6 + k] = (float)(sv / n);
  }
  for (int si = t; si < 5; si += blockDim.x) {  // skew_r / kurt_r
    double dd = (si == 4) ? 64.0 : (double)(1024 >> si);
    double nn = dd * dd;
    double vari = acc[1104 + si * 43] / nn;
    bool cond = (vari / var0) > 1e-6;
    double m3 = acc[1104 + si * 43 + 41] / nn, m4 = acc[1104 + si * 43 + 42] / nn;
    out[1320 + si] = (float)(cond ? m3 / pow(vari, 1.5) : 0.0);
    out[1325 + si] = (float)(cond ? m4 / (vari * vari) : 3.0);
  }
  for (int w = t; w < 656; w += blockDim.x) {  // acm with mirror
    int patch = w / 41, q = w - patch * 41;
    int s = patch >> 2, b = patch & 3;
    double dd = (double)(1024 >> s);
    double v = acc[448 + w] / (dd * dd);
    int di = (q < 5) ? 0 : 1 + (q - 5) / 9;
    int dj = (q < 5) ? q : ((q - 5) % 9) - 4;
    int pi = 4 + di, pj = 4 + dj;
    out[24 + 144 * pi + 16 * pj + 4 * s + b] = (float)v;
    if (q) out[24 + 144 * (8 - pi) + 16 * (8 - pj) + 4 * s + b] = (float)v;
  }
  for (int w = t; w < 205; w += blockDim.x) {  // auto_corr with mirror
    int si = w / 41, q = w - si * 41;
    double dd = (si == 4) ? 64.0 : (double)(1024 >> si);
    double v = acc[1104 + si * 43 + q] / (dd * dd);
    int di = (q < 5) ? 0 : 1 + (q - 5) / 9;
    int dj = (q < 5) ? q : ((q - 5) % 9) - 4;
    int pi = 4 + di, pj = 4 + dj;
    out[1330 + (pi * 9 + pj) * 5 + si] = (float)v;
    if (q) out[1330 + ((8 - pi) * 9 + (8 - pj)) * 5 + si] = (float)v;
  }
  for (int q = t; q < 64; q += blockDim.x) {  // coc_mag
    int s = q >> 4, ij = q & 15;
    double dd = (double)(1024 >> s); double csz = dd * dd;
    out[1735 + ij * 5 + s] = (float)(acc[64 + s * 20 + ij] / csz);
  }
  for (int q = t; q < 64; q += blockDim.x) {  // coc_real s=0..3
    int s = q >> 4, ij = q & 15;
    int i = ij >> 2, j = ij & 3;
    double dd = (double)(1024 >> s); double csz = dd * dd;
    out[1879 + (i * 8 + j) * 5 + s] = (float)(acc[144 + s * 16 + ij] / csz);
  }
  for (int q = t; q < 25; q += blockDim.x) {  // coc_real s=4
    int a = q / 5, b2 = q - a * 5;
    out[1879 + (a * 8 + b2) * 5 + 4] = (float)(acc[390 + q] / 4096.0);
  }
  for (int q = t; q < 48; q += blockDim.x) {  // csc_mag s=0..2
    int s = q >> 4, ij = q & 15;
    int i = ij >> 2, pb = ij & 3;
    double dd = (double)(1024 >> s); double csz = dd * dd;
    const double* ps = acc + 208 + (s * 4 + pb) * 13;
    double meanp = ps[0] / csz;
    double cousSum = acc[64 + s * 20 + 16 + i];
    out[1815 + (i * 4 + pb) * 4 + s] = (float)((ps[1 + i] - meanp * cousSum) / csz);
  }
  for (int q = t; q < 96; q += blockDim.x) {  // csc_real s=0..2
    int s = q >> 5, r = q & 31;
    int i = r >> 3, j = r & 7;
    int pb = j & 3, offq = (j >= 4) ? 9 : 5;
    double dd = (double)(1024 >> s); double csz = dd * dd;
    out[2199 + (i * 8 + j) * 4 + s] = (float)(acc[208 + (s * 4 + pb) * 13 + offq + i] / csz);
  }
  for (int q = t; q < 20; q += blockDim.x) {  // csc_real s=3
    int i = q / 5, c = q - i * 5;
    out[2199 + (i * 8 + c) * 4 + 3] = (float)(acc[370 + q] / 16384.0);
  }
}

// ---------------- host-side helpers ----------------
static void fft_rows(cplx* d, int N, int rows, bool inv, hipStream_t st) {
  dim3 g(rows);
  int T = (N >= 512) ? 256 : ((N == 256) ? 128 : 64);
  dim3 b(T);
  switch (N) {
    case 64:   if (inv) fft_rows_k<6,  true><<<g, b, 0, st>>>(d); else fft_rows_k<6,  false><<<g, b, 0, st>>>(d); break;
    case 128:  if (inv) fft_rows_k<7,  true><<<g, b, 0, st>>>(d); else fft_rows_k<7,  false><<<g, b, 0, st>>>(d); break;
    case 256:  if (inv) fft_rows_k<8,  true><<<g, b, 0, st>>>(d); else fft_rows_k<8,  false><<<g, b, 0, st>>>(d); break;
    case 512:  if (inv) fft_rows_k<9,  true><<<g, b, 0, st>>>(d); else fft_rows_k<9,  false><<<g, b, 0, st>>>(d); break;
    case 1024: if (inv) fft_rows_k<10, true><<<g, b, 0, st>>>(d); else fft_rows_k<10, false><<<g, b, 0, st>>>(d); break;
    default: break;
  }
}
static void fft2d(cplx* a, cplx* b, int N, int P, bool inv, hipStream_t st) {
  fft_rows(a, N, N * P, inv, st);
  dim3 tg(N / 32, N / 32, P), tb(32, 8);
  transpose_k<<<tg, tb, 0, st>>>(b, a, N);
  fft_rows(b, N, N * P, inv, st);
  transpose_k<<<tg, tb, 0, st>>>(a, b, N);
}
static inline dim3 gsz(int n) {
  int b = (n + 255) >> 8;
  if (b > 2048) b = 2048;
  if (b < 1) b = 1;
  return dim3(b);
}

extern "C" void kernel_launch(void* const* d_in, const int* in_sizes, int n_in,
                              void* d_out, int out_size, void* d_ws, size_t ws_size,
                              hipStream_t stream) {
  (void)in_sizes; (void)n_in; (void)out_size; (void)ws_size;
  const float* img = (const float*)d_in[0];
  float* out = (float*)d_out;

  char* wsb = (char*)d_ws;
  size_t off = 0;
  auto alloc = [&](size_t bytes) -> void* {
    void* p = wsb + off;
    off += (bytes + 255) & ~(size_t)255;
    return p;
  };
  const size_t MB = (size_t)1 << 20;
  const int NSLOT = 1320;
  cplx* cA = (cplx*)alloc(16 * MB);
  cplx* cB = (cplx*)alloc(16 * MB);
  cplx* LOD[5];
  for (int s = 0; s < 5; ++s) {
    int N = 1024 >> s;
    LOD[s] = (cplx*)alloc((size_t)N * N * sizeof(cplx));
  }
  cplx* RS[4];  // recon spectra: seed 64^2, then 128^2, 256^2, 512^2 (s=0 goes into cA)
  for (int k = 0; k < 4; ++k) {
    int N = 64 << k;
    RS[k] = (cplx*)alloc((size_t)N * N * sizeof(cplx));
  }
  float* MAG[4];
  float* REALC[4];
  for (int s = 0; s < 4; ++s) {
    int N = 1024 >> s;
    MAG[s] = (float*)alloc((size_t)4 * N * N * sizeof(float));
  }
  for (int s = 0; s < 4; ++s) {
    int N = 1024 >> s;
    REALC[s] = (float*)alloc((size_t)4 * N * N * sizeof(float));
  }
  const int NPIX = 1024 * 1024;
  double* PART = (double*)alloc((size_t)NSLOT * RED_GRID * 8);
  double* ACC  = (double*)alloc(2048 * 8);
  float* MM    = (float*)alloc(256);

  auto finish = [&](int base, int count) {
    reduce_parts_k<<<dim3(count), 64, 0, stream>>>(ACC, PART, base);
  };

  hipMemsetAsync(out, 0, 2456 * sizeof(float), stream);
  init_mm_k<<<1, 64, 0, stream>>>(MM);

  // ---- Phase A: pixel stats ----
  img_stats1_k<<<dim3(RED_GRID), 256, 0, stream>>>(img, NPIX, PART, MM);
  finish(0, 1);
  img_stats2_k<<<dim3(RED_GRID), 256, 0, stream>>>(img, NPIX, ACC, PART);

  // ---- Phase B: steerable pyramid ----
  r2c_k<<<gsz(NPIX), 256, 0, stream>>>(cA, img, NPIX);
  fft2d(cA, cB, 1024, 1, false, stream);
  hp_lo_split_k<<<gsz(NPIX), 256, 0, stream>>>(cA, LOD[0], cA, 10);
  fft2d(cA, cB, 1024, 1, true, stream);
  rhp_stats_k<<<dim3(RED_GRID), 256, 0, stream>>>(cA, NPIX, PART);
  for (int b0 = 0; b0 < 4; b0 += 2) {  // s=0 bands, 2-plane batches
    band_spec_k<<<gsz(NPIX), 256, 0, stream>>>(cA, LOD[0], 10, b0, 2);
    fft2d(cA, cB, 1024, 2, true, stream);
    extract_band_k<2><<<dim3(RED_GRID), 256, 0, stream>>>(REALC[0] + (size_t)b0 * NPIX,
                                                          MAG[0] + (size_t)b0 * NPIX, cA, 20, PART, 8 + b0);
  }
  finish(8, 4);
  center_k<<<gsz(4 * NPIX), 256, 0, stream>>>(MAG[0], 20, 4, ACC + 8);
  lod_down_k<<<gsz(512 * 512), 256, 0, stream>>>(LOD[1], LOD[0], 9);
  for (int s = 1; s <= 3; ++s) {
    int N = 1024 >> s, logN = 10 - s, n = N * N;
    band_spec_k<<<gsz(n), 256, 0, stream>>>(cA, LOD[s], logN, 0, 4);
    fft2d(cA, cB, N, 4, true, stream);
    extract_band_k<4><<<dim3(RED_GRID), 256, 0, stream>>>(REALC[s], MAG[s], cA, 2 * logN, PART, 8 + 4 * s);
    finish(8 + 4 * s, 4);
    center_k<<<gsz(4 * n), 256, 0, stream>>>(MAG[s], 2 * logN, 4, ACC + 8 + 4 * s);
    lod_down_k<<<gsz((N / 2) * (N / 2)), 256, 0, stream>>>(LOD[s + 1], LOD[s], logN - 1);
  }
  // residual lowpass spatial stats (LOD[4] spectrum preserved)
  hipMemcpyAsync(cA, LOD[4], 4096 * sizeof(cplx), hipMemcpyDeviceToDevice, stream);
  fft2d(cA, cB, 64, 1, true, stream);
  sum_real2_k<<<dim3(RED_GRID), 256, 0, stream>>>(cA, 4096, PART);
  finish(24, 1);
  center_abs2_k<<<dim3(RED_GRID), 256, 0, stream>>>(cA, 4096, ACC, PART);

  // ---- acm: all 16 autocorrs in ONE launch (grid z = scale, y = band) ----
  acm_vec_k<<<dim3(RED_GRID, 4, 4), 256, 0, stream>>>(MAG[0], MAG[1], MAG[2], MAG[3], PART);

  // ---- Phase C: recon chain in frequency domain ----
  rs4_init_k<<<gsz(4096), 256, 0, stream>>>(RS[0], LOD[4]);
  hipMemcpyAsync(cA, RS[0], 4096 * sizeof(cplx), hipMemcpyDeviceToDevice, stream);
  fft2d(cA, cB, 64, 1, true, stream);
  ac_rec_k<<<dim3(RED_GRID), 256, 0, stream>>>((const float*)cA, 6, PART, 1104 + 4 * 43);
  cplx* cur = RS[0];
  for (int s = 3; s >= 0; --s) {
    int N = 1024 >> s, logN = 10 - s, n = N * N;
    cplx* nxt = (s > 0) ? RS[4 - s] : cA;
    recon_step_k<<<gsz(n), 256, 0, stream>>>(nxt, cur, LOD[s], logN);
    if (s > 0) {
      hipMemcpyAsync(cA, nxt, (size_t)n * sizeof(cplx), hipMemcpyDeviceToDevice, stream);
    }
    fft2d(cA, cB, N, 1, true, stream);
    ac_rec_k<<<dim3(RED_GRID), 256, 0, stream>>>((const float*)cA, logN, PART, 1104 + s * 43);
    cur = nxt;
  }

  // ---- Phase D: cross-correlations ----
  for (int s = 0; s < 4; ++s) {
    int n = (1024 >> s) * (1024 >> s);
    gram4_k<true><<<dim3(RED_GRID), 256, 0, stream>>>(MAG[s], n, PART, 64 + s * 20);
    gram4_k<false><<<dim3(RED_GRID), 256, 0, stream>>>(REALC[s], n, PART, 144 + s * 16);
  }
  // s=0 parents from LOD[1] (2-plane batches)
  for (int pb0 = 0; pb0 < 4; pb0 += 2) {
    embed_band_k<<<gsz(2 * NPIX), 256, 0, stream>>>(cA, LOD[1], 10, pb0, 2);
    fft2d(cA, cB, 1024, 2, true, stream);
    for (int p = 0; p < 2; ++p)
      parent_reduce_k<<<dim3(RED_GRID), 256, 0, stream>>>(cA + (size_t)p * NPIX, MAG[0], REALC[0], NPIX,
                                                          PART, 208 + (pb0 + p) * 13);
  }
  // s=1,2 parents batched
  for (int s = 1; s <= 2; ++s) {
    int N = 1024 >> s, logN = 10 - s, n = N * N;
    embed_band_k<<<gsz(4 * n), 256, 0, stream>>>(cA, LOD[s + 1], logN, 0, 4);
    fft2d(cA, cB, N, 4, true, stream);
    for (int p = 0; p < 4; ++p)
      parent_reduce_k<<<dim3(RED_GRID), 256, 0, stream>>>(cA + (size_t)p * n, MAG[s], REALC[s], n,
                                                          PART, 208 + (s * 4 + p) * 13);
  }
  // s=3: expanded (centered) lowpass + rolls
  embed_rs_k<<<gsz(128 * 128), 256, 0, stream>>>(cA, LOD[4], 7, 1);
  fft2d(cA, cB, 128, 1, true, stream);
  lp_parent2_k<<<dim3(RED_GRID), 256, 0, stream>>>(cA, REALC[3], 7, PART);

  finish(0, NSLOT);
  assemble_k<<<1, 256, 0, stream>>>(out, ACC, MM);
}

// Round 9
// 1152.316 us; speedup vs baseline: 15.6811x; 1.0557x over previous
//
#include <hip/hip_runtime.h>
#include <math.h>

typedef float2 cplx;

#define PI_F 3.14159265358979323846f
#define SQC  0.8944271909999159f   // sqrt(0.8) = sqrt(2^6 * 3!^2 / (4 * 6!))

#define GS_FOR(i, n) for (int i = blockIdx.x * blockDim.x + threadIdx.x; i < (n); i += gridDim.x * blockDim.x)
#define RED_GRID 256   // all reduction producers use exactly 256 blocks (partials layout)

// FFT pass modes (load-stage fusion)
#define MD_PLAIN 0
#define MD_R2C   1
#define MD_HP    2
#define MD_BAND  3
#define MD_EMB   4

// ---------------- device helpers ----------------
__device__ __forceinline__ float ufreq(int i, int n) {
  return (float)((i < (n >> 1)) ? i : i - n) * (2.0f / (float)n);
}
__device__ __forceinline__ void grid_lr_ang(int i, int j, int n, float* lr, float* ang) {
  float fy = ufreq(i, n), fx = ufreq(j, n);
  float r = sqrtf(fx * fx + fy * fy);
  if (i == 0 && j == 0) r = 1.0f / (float)n;
  *lr = log2f(r);
  *ang = atan2f(fy, fx);
}
__device__ __forceinline__ float rc_hi_f(float lr, float lo, float hi) {
  float t = (lr - lo) / (hi - lo);
  t = fminf(fmaxf(t, 0.0f), 1.0f);
  return sqrtf(0.5f * (1.0f - cosf(PI_F * t)));
}
__device__ __forceinline__ float rc_lo_f(float lr, float lo, float hi) {
  float t = (lr - lo) / (hi - lo);
  t = fminf(fmaxf(t, 0.0f), 1.0f);
  return sqrtf(0.5f * (1.0f + cosf(PI_F * t)));
}
__device__ __forceinline__ float wrap_d(float ang, int b) {
  float d = ang - PI_F * (float)b * 0.25f + PI_F;
  d = d - floorf(d * (0.5f / PI_F)) * (2.0f * PI_F);
  return d - PI_F;
}
__device__ __forceinline__ float amask_c(float ang, int b) {
  float d = wrap_d(ang, b);
  float c = cosf(d);
  float m = 2.0f * SQC * c * c * c;
  return (fabsf(d) < 0.5f * PI_F) ? m : 0.0f;
}
__device__ __forceinline__ float amask_r(float ang, int b) {
  float d = wrap_d(ang, b);
  float c = cosf(d);
  return SQC * c * c * c;
}

__device__ __forceinline__ double wred_d(double v) {
#pragma unroll
  for (int o = 32; o > 0; o >>= 1) v += __shfl_down(v, o);
  return v;
}
// block partial -> PART[slot][256]; NO atomics. blockDim must be 256 (4 waves).
template<int NS>
__device__ __forceinline__ void block_to_parts(double* __restrict__ part, int slotBase, double* v) {
  __shared__ double lds[NS][4];
  const int wid = threadIdx.x >> 6, lane = threadIdx.x & 63;
#pragma unroll
  for (int q = 0; q < NS; ++q) {
    double r = wred_d(v[q]);
    if (lane == 0) lds[q][wid] = r;
  }
  __syncthreads();
  for (int q = threadIdx.x; q < NS; q += blockDim.x) {
    double s = lds[q][0] + lds[q][1] + lds[q][2] + lds[q][3];
    part[(size_t)(slotBase + q) * RED_GRID + blockIdx.x] = s;
  }
}
__global__ void reduce_parts_k(double* __restrict__ acc, const double* __restrict__ part, int base) {
  const double* p = part + (size_t)(base + blockIdx.x) * RED_GRID;
  double s = 0;
  for (int i = threadIdx.x; i < RED_GRID; i += 64) s += p[i];
  s = wred_d(s);
  if (threadIdx.x == 0) acc[base + blockIdx.x] = s;
}
__device__ __forceinline__ void atomicMinF(float* a, float v) {
  if (v >= 0.0f) atomicMin((int*)a, __float_as_int(v));
  else atomicMax((unsigned int*)a, __float_as_uint(v));
}
__device__ __forceinline__ void atomicMaxF(float* a, float v) {
  if (v >= 0.0f) atomicMax((int*)a, __float_as_int(v));
  else atomicMin((unsigned int*)a, __float_as_uint(v));
}

// ---------------- fused FFT row pass: load-modes + radix-2 DIT in LDS ----------------
// Row r = blockIdx.x of (N*P) rows; plane p = r>>LOGN, in-plane row i = r&(N-1).
// MODE selects how element (i,j) of plane p is produced at load time.
template<int LOGN, bool INV, int MODE>
__global__ __launch_bounds__(256) void fftm_k(cplx* __restrict__ dst, const void* __restrict__ srcv,
                                              const cplx* __restrict__ aux, int b0) {
  constexpr int N = 1 << LOGN;
  __shared__ cplx sh[N];
  __shared__ cplx tw[N / 2];
  const int tid = threadIdx.x;
  const int T = blockDim.x;
  const int r = blockIdx.x;
  const int i = r & (N - 1);
  const int p = r >> LOGN;
  for (int k = tid; k < N / 2; k += T) {
    float a = (INV ? 2.0f : -2.0f) * PI_F * (float)k / (float)N;
    float s, c;
    sincosf(a, &s, &c);
    tw[k] = make_float2(c, s);
  }
  for (int j = tid; j < N; j += T) {
    cplx v;
    if (MODE == MD_PLAIN) {
      v = ((const cplx*)srcv)[(size_t)r * N + j];
    } else if (MODE == MD_R2C) {
      v = make_float2(((const float*)srcv)[(size_t)r * N + j], 0.0f);
    } else if (MODE == MD_HP) {
      v = ((const cplx*)srcv)[(size_t)r * N + j];
      float lr, ang;
      grid_lr_ang(i, j, N, &lr, &ang);
      float h0 = rc_hi_f(lr, -1.0f, 0.0f);
      v.x *= h0; v.y *= h0;
    } else if (MODE == MD_BAND) {
      float lr, ang;
      grid_lr_ang(i, j, N, &lr, &ang);
      float m = rc_hi_f(lr, -2.0f, -1.0f) * amask_c(ang, b0 + p);
      cplx z = aux[i * N + j];
      v = make_float2(-z.y * m, z.x * m);   // i*z*m
    } else {  // MD_EMB: embed band spectrum from child lod (Nc = N/2)
      const int Nc = N >> 1, q = Nc >> 1;
      int ci = (i < q) ? i : ((i >= N - q) ? (i - N + Nc) : -1);
      int cj = (j < q) ? j : ((j >= N - q) ? (j - N + Nc) : -1);
      v = make_float2(0.0f, 0.0f);
      if (ci >= 0 && cj >= 0) {
        float lr, ang;
        grid_lr_ang(ci, cj, Nc, &lr, &ang);
        float m = rc_hi_f(lr, -2.0f, -1.0f) * amask_c(ang, b0 + p);
        cplx z = aux[ci * Nc + cj];
        v = make_float2(-z.y * m, z.x * m);
      }
    }
    unsigned rr = __brev((unsigned)j) >> (32 - LOGN);
    sh[rr] = v;
  }
  __syncthreads();
  for (int len = 2; len <= N; len <<= 1) {
    const int half = len >> 1;
    const int tstep = N / len;
    for (int j = tid; j < N / 2; j += T) {
      int pos = j & (half - 1);
      int base = (j - pos) << 1;
      cplx w = tw[pos * tstep];
      cplx a = sh[base + pos];
      cplx b = sh[base + pos + half];
      float tx = b.x * w.x - b.y * w.y;
      float ty = b.x * w.y + b.y * w.x;
      sh[base + pos] = make_float2(a.x + tx, a.y + ty);
      sh[base + pos + half] = make_float2(a.x - tx, a.y - ty);
    }
    __syncthreads();
  }
  const float sc = INV ? (1.0f / (float)N) : 1.0f;
  for (int j = tid; j < N; j += T) {
    cplx v = sh[j];
    dst[(size_t)r * N + j] = make_float2(v.x * sc, v.y * sc);
  }
}

__global__ void transpose_k(cplx* __restrict__ out, const cplx* __restrict__ in, int N) {
  __shared__ cplx tile[32][33];
  size_t po = (size_t)blockIdx.z * N * N;
  int bx = blockIdx.x * 32, by = blockIdx.y * 32;
  int x = bx + threadIdx.x;
  for (int dy = threadIdx.y; dy < 32; dy += 8)
    tile[dy][threadIdx.x] = in[po + (size_t)(by + dy) * N + x];
  __syncthreads();
  int xo = by + threadIdx.x;
  for (int dy = threadIdx.y; dy < 32; dy += 8)
    out[po + (size_t)(bx + dy) * N + xo] = tile[threadIdx.x][dy];
}

// ---------------- pointwise / reduction kernels ----------------
__global__ void lod_only_k(cplx* lod, const cplx* spec, int logN) {
  int N = 1 << logN, n = N * N;
  GS_FOR(idx, n) {
    int i = idx >> logN, j = idx & (N - 1);
    float lr, ang;
    grid_lr_ang(i, j, N, &lr, &ang);
    float l0 = rc_lo_f(lr, -1.0f, 0.0f);
    cplx z = spec[idx];
    lod[idx] = make_float2(z.x * l0, z.y * l0);
  }
}
// slots 4 (sum|rhp|), 5 (sum rhp^2)
__global__ void rhp_stats_k(const cplx* src, int n, double* part) {
  double sa = 0, sq = 0;
  GS_FOR(i, n) {
    float v = src[i].x;
    sa += fabsf(v);
    sq += (double)v * (double)v;
  }
  double v[2] = {sa, sq};
  block_to_parts<2>(part, 4, v);
}
template<int P>
__global__ void extract_band_k(float* realc, float* mag, const cplx* src, int logPer,
                               double* part, int slotBase) {
  int n = (1 << logPer) * P;
  double s0 = 0, s1 = 0, s2 = 0, s3 = 0;
  GS_FOR(idx, n) {
    cplx z = src[idx];
    float m = sqrtf(z.x * z.x + z.y * z.y);
    realc[idx] = z.x;
    mag[idx] = m;
    int p = idx >> logPer;
    if (p == 0) s0 += m; else if (p == 1) s1 += m; else if (p == 2) s2 += m; else s3 += m;
  }
  double v[4] = {s0, s1, s2, s3};
  block_to_parts<P>(part, slotBase, v);
}
__global__ void center_k(float* buf, int logPer, int P, const double* acc0) {
  int nPer = 1 << logPer, n = nPer * P;
  double inv = 1.0 / (double)nPer;
  GS_FOR(idx, n) buf[idx] -= (float)(acc0[idx >> logPer] * inv);
}
__global__ void lod_down_k(cplx* child, const cplx* par, int logNc) {
  int Nc = 1 << logNc, n = Nc * Nc, Np = Nc << 1;
  GS_FOR(idx, n) {
    int i = idx >> logNc, j = idx & (Nc - 1);
    int pi = (i < (Nc >> 1)) ? i : i + Nc;
    int pj = (j < (Nc >> 1)) ? j : j + Nc;
    float lr, ang;
    grid_lr_ang(i, j, Nc, &lr, &ang);
    float l0 = rc_lo_f(lr, -1.0f, 0.0f);
    cplx z = par[pi * Np + pj];
    child[idx] = make_float2(z.x * l0, z.y * l0);
  }
}
__global__ void sum_real2_k(const cplx* src, int n, double* part) {  // slot 24
  double s = 0;
  GS_FOR(i, n) s += (double)src[i].x;
  double v[1] = {s};
  block_to_parts<1>(part, 24, v);
}
__global__ void center_abs2_k(const cplx* src, int n, const double* acc, double* part) {  // slot 25
  float mu = (float)(acc[24] / (double)n);
  double s = 0;
  GS_FOR(i, n) s += fabsf(src[i].x - mu);
  double v[1] = {s};
  block_to_parts<1>(part, 25, v);
}
__global__ void rs4_init_k(cplx* rs, const cplx* lod4) {
  GS_FOR(idx, 4096) {
    int i = idx >> 6, j = idx & 63;
    float lr, ang;
    grid_lr_ang(i, j, 64, &lr, &ang);
    float l0 = rc_lo_f(lr, -1.0f, 0.0f);
    cplx v = lod4[idx];
    if (idx == 0) v = make_float2(0.0f, 0.0f);
    rs[idx] = make_float2(v.x * l0, v.y * l0);
  }
}
__global__ void embed_rs_k(cplx* dst, const cplx* src, int logNb, int zeroDC) {
  int Nb = 1 << logNb, Nc = Nb >> 1, q = Nc >> 1, n = Nb * Nb;
  GS_FOR(idx, n) {
    int i = idx >> logNb, j = idx & (Nb - 1);
    int ci = (i < q) ? i : ((i >= Nb - q) ? (i - Nb + Nc) : -1);
    int cj = (j < q) ? j : ((j >= Nb - q) ? (j - Nb + Nc) : -1);
    cplx v = make_float2(0.0f, 0.0f);
    if (ci >= 0 && cj >= 0) {
      v = src[ci * Nc + cj];
      if (zeroDC && ci == 0 && cj == 0) v = make_float2(0.0f, 0.0f);
    }
    dst[idx] = v;
  }
}
// fused: dst = embed(src into 2x grid) + recon-band spectrum from lod (canonical)
__global__ void recon_step_k(cplx* __restrict__ dst, const cplx* __restrict__ src,
                             const cplx* __restrict__ lod, int logNb) {
  int Nb = 1 << logNb, Nc = Nb >> 1, qq = Nc >> 1, n = Nb * Nb;
  GS_FOR(idx, n) {
    int i = idx >> logNb, j = idx & (Nb - 1);
    int ci = (i < qq) ? i : ((i >= Nb - qq) ? (i - Nb + Nc) : -1);
    int cj = (j < qq) ? j : ((j >= Nb - qq) ? (j - Nb + Nc) : -1);
    float ex = 0.0f, ey = 0.0f;
    if (ci >= 0 && cj >= 0) { cplx v = src[ci * Nc + cj]; ex = v.x; ey = v.y; }
    int ni = (Nb - i) & (Nb - 1), nj = (Nb - j) & (Nb - 1);
    float lr, ang;
    grid_lr_ang(i, j, Nb, &lr, &ang);
    float him = rc_hi_f(lr, -2.0f, -1.0f);
    float l0 = rc_lo_f(lr, -1.0f, 0.0f);
    cplx L = lod[idx];
    cplx L2 = lod[ni * Nb + nj];
    float sx = 0.0f, sy = 0.0f;
#pragma unroll
    for (int b = 0; b < 4; ++b) {
      float c1 = him * amask_c(ang, b);
      float c2 = him * amask_c(ang + PI_F, b);
      float mr = him * amask_r(ang, b);
      float gx = L.x * c1 - L2.x * c2;
      float gy = L.y * c1 + L2.y * c2;
      sx += 0.5f * mr * gx;
      sy += 0.5f * mr * gy;
    }
    dst[idx] = make_float2(ex + sx * l0, ey + sy * l0);
  }
}
// ---- vectorized spatial autocorrelation core (fields stored TRANSPOSED; fixed in assemble) ----
template<int ST, bool SK>
__device__ __forceinline__ void ac_core(const float* __restrict__ xp, int logN,
                                        double* __restrict__ part, int slotBase) {
  const int N = 1 << logN;
  const int nu = (N * N) >> 3;
  float acc[41];
#pragma unroll
  for (int q = 0; q < 41; ++q) acc[q] = 0.0f;
  float a3 = 0.0f, a4 = 0.0f;
  for (int u = blockIdx.x * blockDim.x + threadIdx.x; u < nu; u += gridDim.x * blockDim.x) {
    int i = u >> (logN - 3);
    int j0 = (u & ((N >> 3) - 1)) << 3;
    float buf[5][16];
#pragma unroll
    for (int di = 0; di < 5; ++di) {
      int r = ((i + di) & (N - 1)) << logN;
#pragma unroll
      for (int blk = 0; blk < 4; ++blk) {
        int c = (j0 - 4 + blk * 4) & (N - 1);   // 4-aligned, never straddles wrap
        if (ST == 1) {
          const float4 v = *reinterpret_cast<const float4*>(xp + r + c);
          buf[di][blk * 4 + 0] = v.x; buf[di][blk * 4 + 1] = v.y;
          buf[di][blk * 4 + 2] = v.z; buf[di][blk * 4 + 3] = v.w;
        } else {
          const float4 v0 = *reinterpret_cast<const float4*>(xp + ((size_t)(r + c) << 1));
          const float4 v1 = *reinterpret_cast<const float4*>(xp + ((size_t)(r + c) << 1) + 4);
          buf[di][blk * 4 + 0] = v0.x; buf[di][blk * 4 + 1] = v0.z;
          buf[di][blk * 4 + 2] = v1.x; buf[di][blk * 4 + 3] = v1.z;
        }
      }
    }
#pragma unroll
    for (int k = 0; k < 8; ++k) {
      float xc = buf[0][4 + k];
      if (SK) {
        float x2 = xc * xc;
        a3 += x2 * xc;
        a4 += x2 * x2;
      }
#pragma unroll
      for (int q = 0; q < 41; ++q) {
        const int di = (q < 5) ? 0 : 1 + (q - 5) / 9;
        const int dj = (q < 5) ? q : ((q - 5) % 9) - 4;
        acc[q] += xc * buf[di][4 + k + dj];
      }
    }
  }
  constexpr int NS = SK ? 43 : 41;
  double v[NS];
#pragma unroll
  for (int q = 0; q < 41; ++q) v[q] = (double)acc[q];
  if (SK) { v[41] = (double)a3; v[42] = (double)a4; }
  block_to_parts<NS>(part, slotBase, v);
}
__global__ __launch_bounds__(256) void acm_vec_k(const float* m0, const float* m1,
                                                 const float* m2, const float* m3, double* part) {
  const int s = blockIdx.z;
  const float* base = (s == 0) ? m0 : ((s == 1) ? m1 : ((s == 2) ? m2 : m3));
  const int logN = 10 - s;
  const float* xp = base + ((size_t)blockIdx.y << (2 * logN));
  ac_core<1, false>(xp, logN, part, 448 + (s * 4 + blockIdx.y) * 41);
}
__global__ __launch_bounds__(256) void ac_rec_k(const float* x, int logN, double* part, int slotBase) {
  ac_core<2, true>(x, logN, part, slotBase);
}
__global__ void img_stats1_k(const float* img, int n, double* part, float* mm) {  // slot 0
  double s = 0;
  float mn = INFINITY, mx = -INFINITY;
  GS_FOR(i, n) {
    float v = img[i];
    s += (double)v;
    mn = fminf(mn, v);
    mx = fmaxf(mx, v);
  }
  double v[1] = {s};
  block_to_parts<1>(part, 0, v);
#pragma unroll
  for (int o = 32; o > 0; o >>= 1) {
    mn = fminf(mn, __shfl_down(mn, o));
    mx = fmaxf(mx, __shfl_down(mx, o));
  }
  if ((threadIdx.x & 63) == 0) {
    atomicMinF(mm + 0, mn);
    atomicMaxF(mm + 1, mx);
  }
}
__global__ void img_stats2_k(const float* img, int n, const double* acc, double* part) {  // slots 1..3
  double mu = acc[0] / (double)n;
  double s2 = 0, s3 = 0, s4 = 0;
  GS_FOR(i, n) {
    double c = (double)img[i] - mu;
    double c2 = c * c;
    s2 += c2;
    s3 += c2 * c;
    s4 += c2 * c2;
  }
  double v[3] = {s2, s3, s4};
  block_to_parts<3>(part, 1, v);
}
template<bool WS>
__global__ void gram4_k(const float* base, int n, double* part, int slotBase) {
  constexpr int NS = WS ? 20 : 16;
  double g[16];
  double s[4];
#pragma unroll
  for (int q = 0; q < 16; ++q) g[q] = 0;
#pragma unroll
  for (int q = 0; q < 4; ++q) s[q] = 0;
  GS_FOR(i, n) {
    double d0 = base[i], d1 = base[n + i], d2 = base[2 * n + i], d3 = base[3 * n + i];
    g[0] += d0 * d0; g[1] += d0 * d1; g[2]  += d0 * d2; g[3]  += d0 * d3;
    g[5] += d1 * d1; g[6] += d1 * d2; g[7]  += d1 * d3;
    g[10] += d2 * d2; g[11] += d2 * d3;
    g[15] += d3 * d3;
    if (WS) { s[0] += d0; s[1] += d1; s[2] += d2; s[3] += d3; }
  }
  g[4] = g[1]; g[8] = g[2]; g[12] = g[3]; g[9] = g[6]; g[13] = g[7]; g[14] = g[11];
  double v[NS];
#pragma unroll
  for (int q = 0; q < 16; ++q) v[q] = g[q];
  if (WS) {
#pragma unroll
    for (int q = 0; q < 4; ++q) v[16 + q] = s[q];
  }
  block_to_parts<NS>(part, slotBase, v);
}
__global__ void parent_reduce_k(const cplx* par, const float* magS, const float* realS, int n,
                                double* part, int slotBase) {
  double d[13];
#pragma unroll
  for (int q = 0; q < 13; ++q) d[q] = 0;
  GS_FOR(i, n) {
    cplx z = par[i];
    float rt = z.x, it = z.y;
    float mg = sqrtf(rt * rt + it * it);
    float rpr = 0.0f, rpi = 0.0f;
    if (mg > 0.0f) {
      rpr = (it * it - rt * rt) / mg;
      rpi = 2.0f * rt * it / mg;
    }
    d[0] += (double)mg;
#pragma unroll
    for (int b = 0; b < 4; ++b) d[1 + b] += (double)magS[b * n + i] * (double)mg;
#pragma unroll
    for (int b = 0; b < 4; ++b) {
      double rv = (double)realS[b * n + i];
      d[5 + b] += rv * (double)rpr;
      d[9 + b] += rv * (double)rpi;
    }
  }
  block_to_parts<13>(part, slotBase, d);
}
// lowpass parents on TRANSPOSED X: rolls on stored axes match reference's tmp=X.T directly
__global__ void lp_parent2_k(const cplx* X, const float* realS, int logN, double* part) {  // slots 370..414
  int N = 1 << logN, n = N * N;
  double d[45];
#pragma unroll
  for (int q = 0; q < 45; ++q) d[q] = 0;
  GS_FOR(idx, n) {
    int i = idx >> logN, j = idx & (N - 1);
    float c[5];
    c[0] = X[idx].x;
    c[1] = X[((i - 1) & (N - 1)) * N + j].x;   // roll +1 axis0 (stored)
    c[2] = X[((i + 1) & (N - 1)) * N + j].x;   // roll -1 axis0
    c[3] = X[i * N + ((j - 1) & (N - 1))].x;   // roll +1 axis1
    c[4] = X[i * N + ((j + 1) & (N - 1))].x;   // roll -1 axis1
#pragma unroll
    for (int b = 0; b < 4; ++b) {
      double rv = (double)realS[b * n + idx];
#pragma unroll
      for (int k = 0; k < 5; ++k) d[b * 5 + k] += rv * (double)c[k];
    }
#pragma unroll
    for (int a = 0; a < 5; ++a)
#pragma unroll
      for (int k = 0; k < 5; ++k) d[20 + a * 5 + k] += (double)c[a] * (double)c[k];
  }
  block_to_parts<45>(part, 370, d);
}
__global__ void init_mm_k(float* mm) {
  if (threadIdx.x == 0) { mm[0] = INFINITY; mm[1] = -INFINITY; }
}

// ---------------- final assembly ----------------
// Spatial fields are stored TRANSPOSED: stored ac offset (di,dj) == physical (dj,di),
// so patch writes swap the roles of di/dj vs the canonical version (which passed tests).
__global__ void assemble_k(float* out, const double* acc, const float* mm) {
  const int t = threadIdx.x;
  const double NPIX = 1048576.0;
  double var0 = acc[1] / (NPIX - 1.0);
  if (t == 0) {
    double mu = acc[0] / NPIX;
    out[0] = (float)mu;
    out[1] = (float)var0;
    out[2] = (float)((acc[2] / NPIX) / pow(var0, 1.5));
    out[3] = (float)((acc[3] / NPIX) / (var0 * var0));
    out[4] = mm[0];
    out[5] = mm[1];
    out[2455] = (float)(acc[5] / NPIX);  // var_hp
  }
  for (int k = t; k < 18; k += blockDim.x) {  // mag_means
    double n, sv;
    if (k == 0) { n = NPIX; sv = acc[4]; }
    else if (k == 17) { n = 4096.0; sv = acc[25]; }
    else { int s = (k - 1) >> 2; double dd = (double)(1024 >> s); n = dd * dd; sv = acc[7 + k]; }
    out[6 + k] = (float)(sv / n);
  }
  for (int si = t; si < 5; si += blockDim.x) {  // skew_r / kurt_r
    double dd = (si == 4) ? 64.0 : (double)(1024 >> si);
    double nn = dd * dd;
    double vari = acc[1104 + si * 43] / nn;
    bool cond = (vari / var0) > 1e-6;
    double m3 = acc[1104 + si * 43 + 41] / nn, m4 = acc[1104 + si * 43 + 42] / nn;
    out[1320 + si] = (float)(cond ? m3 / pow(vari, 1.5) : 0.0);
    out[1325 + si] = (float)(cond ? m4 / (vari * vari) : 3.0);
  }
  for (int w = t; w < 656; w += blockDim.x) {  // acm (transposed: swap di/dj)
    int patch = w / 41, q = w - patch * 41;
    int s = patch >> 2, b = patch & 3;
    double dd = (double)(1024 >> s);
    double v = acc[448 + w] / (dd * dd);
    int di = (q < 5) ? 0 : 1 + (q - 5) / 9;
    int dj = (q < 5) ? q : ((q - 5) % 9) - 4;
    int pi = 4 + dj, pj = 4 + di;        // SWAPPED for transposed storage
    out[24 + 144 * pi + 16 * pj + 4 * s + b] = (float)v;
    if (q) out[24 + 144 * (8 - pi) + 16 * (8 - pj) + 4 * s + b] = (float)v;
  }
  for (int w = t; w < 205; w += blockDim.x) {  // auto_corr (transposed: swap di/dj)
    int si = w / 41, q = w - si * 41;
    double dd = (si == 4) ? 64.0 : (double)(1024 >> si);
    double v = acc[1104 + si * 43 + q] / (dd * dd);
    int di = (q < 5) ? 0 : 1 + (q - 5) / 9;
    int dj = (q < 5) ? q : ((q - 5) % 9) - 4;
    int pi = 4 + dj, pj = 4 + di;        // SWAPPED
    out[1330 + (pi * 9 + pj) * 5 + si] = (float)v;
    if (q) out[1330 + ((8 - pi) * 9 + (8 - pj)) * 5 + si] = (float)v;
  }
  for (int q = t; q < 64; q += blockDim.x) {  // coc_mag
    int s = q >> 4, ij = q & 15;
    double dd = (double)(1024 >> s); double csz = dd * dd;
    out[1735 + ij * 5 + s] = (float)(acc[64 + s * 20 + ij] / csz);
  }
  for (int q = t; q < 64; q += blockDim.x) {  // coc_real s=0..3
    int s = q >> 4, ij = q & 15;
    int i = ij >> 2, j = ij & 3;
    double dd = (double)(1024 >> s); double csz = dd * dd;
    out[1879 + (i * 8 + j) * 5 + s] = (float)(acc[144 + s * 16 + ij] / csz);
  }
  for (int q = t; q < 25; q += blockDim.x) {  // coc_real s=4
    int a = q / 5, b2 = q - a * 5;
    out[1879 + (a * 8 + b2) * 5 + 4] = (float)(acc[390 + q] / 4096.0);
  }
  for (int q = t; q < 48; q += blockDim.x) {  // csc_mag s=0..2
    int s = q >> 4, ij = q & 15;
    int i = ij >> 2, pb = ij & 3;
    double dd = (double)(1024 >> s); double csz = dd * dd;
    const double* ps = acc + 208 + (s * 4 + pb) * 13;
    double meanp = ps[0] / csz;
    double cousSum = acc[64 + s * 20 + 16 + i];
    out[1815 + (i * 4 + pb) * 4 + s] = (float)((ps[1 + i] - meanp * cousSum) / csz);
  }
  for (int q = t; q < 96; q += blockDim.x) {  // csc_real s=0..2
    int s = q >> 5, r = q & 31;
    int i = r >> 3, j = r & 7;
    int pb = j & 3, offq = (j >= 4) ? 9 : 5;
    double dd = (double)(1024 >> s); double csz = dd * dd;
    out[2199 + (i * 8 + j) * 4 + s] = (float)(acc[208 + (s * 4 + pb) * 13 + offq + i] / csz);
  }
  for (int q = t; q < 20; q += blockDim.x) {  // csc_real s=3
    int i = q / 5, c = q - i * 5;
    out[2199 + (i * 8 + c) * 4 + 3] = (float)(acc[370 + q] / 16384.0);
  }
}

// ---------------- host-side FFT dispatch ----------------
static inline int thr_for(int N) { return (N >= 512) ? 256 : ((N == 256) ? 128 : 64); }
template<int MODE>
static void fft_pass(int N, int rows, bool inv, cplx* dst, const void* src, const cplx* aux,
                     int b0, hipStream_t st) {
  dim3 g(rows), b(thr_for(N));
  switch (N) {
    case 64:
      if (inv) fftm_k<6, true, MODE><<<g, b, 0, st>>>(dst, src, aux, b0);
      else     fftm_k<6, false, MODE><<<g, b, 0, st>>>(dst, src, aux, b0);
      break;
    case 128:
      if (inv) fftm_k<7, true, MODE><<<g, b, 0, st>>>(dst, src, aux, b0);
      else     fftm_k<7, false, MODE><<<g, b, 0, st>>>(dst, src, aux, b0);
      break;
    case 256:
      if (inv) fftm_k<8, true, MODE><<<g, b, 0, st>>>(dst, src, aux, b0);
      else     fftm_k<8, false, MODE><<<g, b, 0, st>>>(dst, src, aux, b0);
      break;
    case 512:
      if (inv) fftm_k<9, true, MODE><<<g, b, 0, st>>>(dst, src, aux, b0);
      else     fftm_k<9, false, MODE><<<g, b, 0, st>>>(dst, src, aux, b0);
      break;
    case 1024:
      if (inv) fftm_k<10, true, MODE><<<g, b, 0, st>>>(dst, src, aux, b0);
      else     fftm_k<10, false, MODE><<<g, b, 0, st>>>(dst, src, aux, b0);
      break;
    default: break;
  }
}
static void transp(cplx* out, const cplx* in, int N, int P, hipStream_t st) {
  dim3 tg(N / 32, N / 32, P), tb(32, 8);
  transpose_k<<<tg, tb, 0, st>>>(out, in, N);
}
// ifft2 producing TRANSPOSED spatial output in `out` (3 dispatches; src preserved unless src==out)
template<int MODE>
static void ifft2dT(int N, int P, cplx* out, cplx* tmp, const void* src, const cplx* aux,
                    int b0, hipStream_t st) {
  fft_pass<MODE>(N, N * P, true, tmp, src, aux, b0, st);
  transp(out, tmp, N, P, st);
  fft_pass<MD_PLAIN>(N, N * P, true, out, out, nullptr, 0, st);
}
static inline dim3 gsz(int n) {
  int b = (n + 255) >> 8;
  if (b > 2048) b = 2048;
  if (b < 1) b = 1;
  return dim3(b);
}

extern "C" void kernel_launch(void* const* d_in, const int* in_sizes, int n_in,
                              void* d_out, int out_size, void* d_ws, size_t ws_size,
                              hipStream_t stream) {
  (void)in_sizes; (void)n_in; (void)out_size; (void)ws_size;
  const float* img = (const float*)d_in[0];
  float* out = (float*)d_out;

  char* wsb = (char*)d_ws;
  size_t off = 0;
  auto alloc = [&](size_t bytes) -> void* {
    void* p = wsb + off;
    off += (bytes + 255) & ~(size_t)255;
    return p;
  };
  const size_t MB = (size_t)1 << 20;
  const int NSLOT = 1320;
  cplx* cA = (cplx*)alloc(16 * MB);
  cplx* cB = (cplx*)alloc(16 * MB);
  cplx* LOD[5];
  for (int s = 0; s < 5; ++s) {
    int N = 1024 >> s;
    LOD[s] = (cplx*)alloc((size_t)N * N * sizeof(cplx));
  }
  cplx* RS[4];  // recon spectra 64^2..512^2 (s=0 spectrum lives in cB transiently)
  for (int k = 0; k < 4; ++k) {
    int N = 64 << k;
    RS[k] = (cplx*)alloc((size_t)N * N * sizeof(cplx));
  }
  float* MAG[4];
  float* REALC[4];
  for (int s = 0; s < 4; ++s) {
    int N = 1024 >> s;
    MAG[s] = (float*)alloc((size_t)4 * N * N * sizeof(float));
  }
  for (int s = 0; s < 4; ++s) {
    int N = 1024 >> s;
    REALC[s] = (float*)alloc((size_t)4 * N * N * sizeof(float));
  }
  const int NPIX = 1024 * 1024;
  double* PART = (double*)alloc((size_t)NSLOT * RED_GRID * 8);
  double* ACC  = (double*)alloc(2048 * 8);
  float* MM    = (float*)alloc(256);

  auto finish = [&](int base, int count) {
    reduce_parts_k<<<dim3(count), 64, 0, stream>>>(ACC, PART, base);
  };

  hipMemsetAsync(out, 0, 2456 * sizeof(float), stream);
  init_mm_k<<<1, 64, 0, stream>>>(MM);

  // ---- Phase A: pixel stats ----
  img_stats1_k<<<dim3(RED_GRID), 256, 0, stream>>>(img, NPIX, PART, MM);
  finish(0, 1);
  img_stats2_k<<<dim3(RED_GRID), 256, 0, stream>>>(img, NPIX, ACC, PART);

  // ---- Phase B: forward FFT (canonical spectrum in cA) ----
  fft_pass<MD_R2C>(1024, 1024, false, cA, img, nullptr, 0, stream);
  transp(cB, cA, 1024, 1, stream);
  fft_pass<MD_PLAIN>(1024, 1024, false, cB, cB, nullptr, 0, stream);
  transp(cA, cB, 1024, 1, stream);
  lod_only_k<<<gsz(NPIX), 256, 0, stream>>>(LOD[0], cA, 10);
  // residual highpass: HP-fused ifft (out=cA transposed; spectrum consumed)
  ifft2dT<MD_HP>(1024, 1, cA, cB, cA, nullptr, 0, stream);
  rhp_stats_k<<<dim3(RED_GRID), 256, 0, stream>>>(cA, NPIX, PART);
  // s=0 bands: BAND-fused ifft, 2-plane batches
  for (int b0 = 0; b0 < 4; b0 += 2) {
    ifft2dT<MD_BAND>(1024, 2, cB, cA, nullptr, LOD[0], b0, stream);
    extract_band_k<2><<<dim3(RED_GRID), 256, 0, stream>>>(REALC[0] + (size_t)b0 * NPIX,
                                                          MAG[0] + (size_t)b0 * NPIX, cB, 20, PART, 8 + b0);
  }
  finish(8, 4);
  center_k<<<gsz(4 * NPIX), 256, 0, stream>>>(MAG[0], 20, 4, ACC + 8);
  lod_down_k<<<gsz(512 * 512), 256, 0, stream>>>(LOD[1], LOD[0], 9);
  for (int s = 1; s <= 3; ++s) {
    int N = 1024 >> s, logN = 10 - s, n = N * N;
    ifft2dT<MD_BAND>(N, 4, cB, cA, nullptr, LOD[s], 0, stream);
    extract_band_k<4><<<dim3(RED_GRID), 256, 0, stream>>>(REALC[s], MAG[s], cB, 2 * logN, PART, 8 + 4 * s);
    finish(8 + 4 * s, 4);
    center_k<<<gsz(4 * n), 256, 0, stream>>>(MAG[s], 2 * logN, 4, ACC + 8 + 4 * s);
    lod_down_k<<<gsz((N / 2) * (N / 2)), 256, 0, stream>>>(LOD[s + 1], LOD[s], logN - 1);
  }
  // residual lowpass spatial stats (LOD[4] preserved)
  ifft2dT<MD_PLAIN>(64, 1, cB, cA, LOD[4], nullptr, 0, stream);
  sum_real2_k<<<dim3(RED_GRID), 256, 0, stream>>>(cB, 4096, PART);
  finish(24, 1);
  center_abs2_k<<<dim3(RED_GRID), 256, 0, stream>>>(cB, 4096, ACC, PART);

  // ---- acm: all 16 autocorrs, one launch ----
  acm_vec_k<<<dim3(RED_GRID, 4, 4), 256, 0, stream>>>(MAG[0], MAG[1], MAG[2], MAG[3], PART);

  // ---- Phase C: recon chain (spectra canonical; spatial ACs on transposed ifft outputs) ----
  rs4_init_k<<<gsz(4096), 256, 0, stream>>>(RS[0], LOD[4]);
  ifft2dT<MD_PLAIN>(64, 1, cB, cA, RS[0], nullptr, 0, stream);
  ac_rec_k<<<dim3(RED_GRID), 256, 0, stream>>>((const float*)cB, 6, PART, 1104 + 4 * 43);
  cplx* cur = RS[0];
  for (int s = 3; s >= 0; --s) {
    int N = 1024 >> s, logN = 10 - s, n = N * N;
    cplx* sp = (s > 0) ? RS[4 - s] : cB;   // s=0 spectrum is transient in cB
    recon_step_k<<<gsz(n), 256, 0, stream>>>(sp, cur, LOD[s], logN);
    ifft2dT<MD_PLAIN>(N, 1, cB, cA, sp, nullptr, 0, stream);
    ac_rec_k<<<dim3(RED_GRID), 256, 0, stream>>>((const float*)cB, logN, PART, 1104 + s * 43);
    cur = sp;
  }

  // ---- Phase D: cross-correlations ----
  for (int s = 0; s < 4; ++s) {
    int n = (1024 >> s) * (1024 >> s);
    gram4_k<true><<<dim3(RED_GRID), 256, 0, stream>>>(MAG[s], n, PART, 64 + s * 20);
    gram4_k<false><<<dim3(RED_GRID), 256, 0, stream>>>(REALC[s], n, PART, 144 + s * 16);
  }
  // s=0 parents: EMB-fused ifft from LOD[1], 2-plane batches
  for (int pb0 = 0; pb0 < 4; pb0 += 2) {
    ifft2dT<MD_EMB>(1024, 2, cB, cA, nullptr, LOD[1], pb0, stream);
    for (int p = 0; p < 2; ++p)
      parent_reduce_k<<<dim3(RED_GRID), 256, 0, stream>>>(cB + (size_t)p * NPIX, MAG[0], REALC[0], NPIX,
                                                          PART, 208 + (pb0 + p) * 13);
  }
  // s=1,2 parents: EMB-fused ifft, 4-plane batch
  for (int s = 1; s <= 2; ++s) {
    int N = 1024 >> s, n = N * N;
    ifft2dT<MD_EMB>(N, 4, cB, cA, nullptr, LOD[s + 1], 0, stream);
    for (int p = 0; p < 4; ++p)
      parent_reduce_k<<<dim3(RED_GRID), 256, 0, stream>>>(cB + (size_t)p * n, MAG[s], REALC[s], n,
                                                          PART, 208 + (s * 4 + p) * 13);
  }
  // s=3: expanded (centered) lowpass + rolls (transposed; rolls handled in lp_parent2_k)
  embed_rs_k<<<gsz(128 * 128), 256, 0, stream>>>(cA, LOD[4], 7, 1);
  ifft2dT<MD_PLAIN>(128, 1, cB, cA + 16384, cA, nullptr, 0, stream);
  lp_parent2_k<<<dim3(RED_GRID), 256, 0, stream>>>(cB, REALC[3], 7, PART);

  finish(0, NSLOT);
  assemble_k<<<1, 256, 0, stream>>>(out, ACC, MM);
}

// Round 10
// 1068.842 us; speedup vs baseline: 16.9058x; 1.0781x over previous
//
#include <hip/hip_runtime.h>
#include <math.h>

typedef float2 cplx;

#define PI_F 3.14159265358979323846f
#define SQC  0.8944271909999159f   // sqrt(0.8) = sqrt(2^6 * 3!^2 / (4 * 6!))

#define GS_FOR(i, n) for (int i = blockIdx.x * blockDim.x + threadIdx.x; i < (n); i += gridDim.x * blockDim.x)
#define RED_GRID 512   // all reduction producers use exactly 512 blocks (partials layout)

// FFT pass modes (load-stage fusion)
#define MD_PLAIN 0
#define MD_R2C   1
#define MD_HP    2
#define MD_BAND  3
#define MD_EMB   4

// ---------------- device helpers ----------------
__device__ __forceinline__ float ufreq(int i, int n) {
  return (float)((i < (n >> 1)) ? i : i - n) * (2.0f / (float)n);
}
__device__ __forceinline__ void grid_lr_ang(int i, int j, int n, float* lr, float* ang) {
  float fy = ufreq(i, n), fx = ufreq(j, n);
  float r = sqrtf(fx * fx + fy * fy);
  if (i == 0 && j == 0) r = 1.0f / (float)n;
  *lr = log2f(r);
  *ang = atan2f(fy, fx);
}
__device__ __forceinline__ float rc_hi_f(float lr, float lo, float hi) {
  float t = (lr - lo) / (hi - lo);
  t = fminf(fmaxf(t, 0.0f), 1.0f);
  return sqrtf(0.5f * (1.0f - cosf(PI_F * t)));
}
__device__ __forceinline__ float rc_lo_f(float lr, float lo, float hi) {
  float t = (lr - lo) / (hi - lo);
  t = fminf(fmaxf(t, 0.0f), 1.0f);
  return sqrtf(0.5f * (1.0f + cosf(PI_F * t)));
}
__device__ __forceinline__ float wrap_d(float ang, int b) {
  float d = ang - PI_F * (float)b * 0.25f + PI_F;
  d = d - floorf(d * (0.5f / PI_F)) * (2.0f * PI_F);
  return d - PI_F;
}
__device__ __forceinline__ float amask_c(float ang, int b) {
  float d = wrap_d(ang, b);
  float c = cosf(d);
  float m = 2.0f * SQC * c * c * c;
  return (fabsf(d) < 0.5f * PI_F) ? m : 0.0f;
}
__device__ __forceinline__ float amask_r(float ang, int b) {
  float d = wrap_d(ang, b);
  float c = cosf(d);
  return SQC * c * c * c;
}

__device__ __forceinline__ double wred_d(double v) {
#pragma unroll
  for (int o = 32; o > 0; o >>= 1) v += __shfl_down(v, o);
  return v;
}
// block partial -> PART[slot][RED_GRID]; NO atomics. blockDim must be 256 (4 waves).
template<int NS>
__device__ __forceinline__ void block_to_parts(double* __restrict__ part, int slotBase, double* v) {
  __shared__ double lds[NS][4];
  const int wid = threadIdx.x >> 6, lane = threadIdx.x & 63;
#pragma unroll
  for (int q = 0; q < NS; ++q) {
    double r = wred_d(v[q]);
    if (lane == 0) lds[q][wid] = r;
  }
  __syncthreads();
  for (int q = threadIdx.x; q < NS; q += blockDim.x) {
    double s = lds[q][0] + lds[q][1] + lds[q][2] + lds[q][3];
    part[(size_t)(slotBase + q) * RED_GRID + blockIdx.x] = s;
  }
}
__global__ void reduce_parts_k(double* __restrict__ acc, const double* __restrict__ part, int base) {
  const double* p = part + (size_t)(base + blockIdx.x) * RED_GRID;
  double s = 0;
  for (int i = threadIdx.x; i < RED_GRID; i += 64) s += p[i];
  s = wred_d(s);
  if (threadIdx.x == 0) acc[base + blockIdx.x] = s;
}
__device__ __forceinline__ void atomicMinF(float* a, float v) {
  if (v >= 0.0f) atomicMin((int*)a, __float_as_int(v));
  else atomicMax((unsigned int*)a, __float_as_uint(v));
}
__device__ __forceinline__ void atomicMaxF(float* a, float v) {
  if (v >= 0.0f) atomicMax((int*)a, __float_as_int(v));
  else atomicMin((unsigned int*)a, __float_as_uint(v));
}

// ---------------- fused FFT row pass: load-modes + radix-2 DIT in LDS ----------------
template<int LOGN, bool INV, int MODE>
__global__ __launch_bounds__(256) void fftm_k(cplx* __restrict__ dst, const void* __restrict__ srcv,
                                              const cplx* __restrict__ aux, int b0) {
  constexpr int N = 1 << LOGN;
  __shared__ cplx sh[N];
  __shared__ cplx tw[N / 2];
  const int tid = threadIdx.x;
  const int T = blockDim.x;
  const int r = blockIdx.x;
  const int i = r & (N - 1);
  const int p = r >> LOGN;
  for (int k = tid; k < N / 2; k += T) {
    float a = (INV ? 2.0f : -2.0f) * PI_F * (float)k / (float)N;
    float s, c;
    sincosf(a, &s, &c);
    tw[k] = make_float2(c, s);
  }
  for (int j = tid; j < N; j += T) {
    cplx v;
    if (MODE == MD_PLAIN) {
      v = ((const cplx*)srcv)[(size_t)r * N + j];
    } else if (MODE == MD_R2C) {
      v = make_float2(((const float*)srcv)[(size_t)r * N + j], 0.0f);
    } else if (MODE == MD_HP) {
      v = ((const cplx*)srcv)[(size_t)r * N + j];
      float lr, ang;
      grid_lr_ang(i, j, N, &lr, &ang);
      float h0 = rc_hi_f(lr, -1.0f, 0.0f);
      v.x *= h0; v.y *= h0;
    } else if (MODE == MD_BAND) {
      float lr, ang;
      grid_lr_ang(i, j, N, &lr, &ang);
      float m = rc_hi_f(lr, -2.0f, -1.0f) * amask_c(ang, b0 + p);
      cplx z = aux[i * N + j];
      v = make_float2(-z.y * m, z.x * m);   // i*z*m
    } else {  // MD_EMB
      const int Nc = N >> 1, q = Nc >> 1;
      int ci = (i < q) ? i : ((i >= N - q) ? (i - N + Nc) : -1);
      int cj = (j < q) ? j : ((j >= N - q) ? (j - N + Nc) : -1);
      v = make_float2(0.0f, 0.0f);
      if (ci >= 0 && cj >= 0) {
        float lr, ang;
        grid_lr_ang(ci, cj, Nc, &lr, &ang);
        float m = rc_hi_f(lr, -2.0f, -1.0f) * amask_c(ang, b0 + p);
        cplx z = aux[ci * Nc + cj];
        v = make_float2(-z.y * m, z.x * m);
      }
    }
    unsigned rr = __brev((unsigned)j) >> (32 - LOGN);
    sh[rr] = v;
  }
  __syncthreads();
  for (int len = 2; len <= N; len <<= 1) {
    const int half = len >> 1;
    const int tstep = N / len;
    for (int j = tid; j < N / 2; j += T) {
      int pos = j & (half - 1);
      int base = (j - pos) << 1;
      cplx w = tw[pos * tstep];
      cplx a = sh[base + pos];
      cplx b = sh[base + pos + half];
      float tx = b.x * w.x - b.y * w.y;
      float ty = b.x * w.y + b.y * w.x;
      sh[base + pos] = make_float2(a.x + tx, a.y + ty);
      sh[base + pos + half] = make_float2(a.x - tx, a.y - ty);
    }
    __syncthreads();
  }
  const float sc = INV ? (1.0f / (float)N) : 1.0f;
  for (int j = tid; j < N; j += T) {
    cplx v = sh[j];
    dst[(size_t)r * N + j] = make_float2(v.x * sc, v.y * sc);
  }
}

__global__ void transpose_k(cplx* __restrict__ out, const cplx* __restrict__ in, int N) {
  __shared__ cplx tile[32][33];
  size_t po = (size_t)blockIdx.z * N * N;
  int bx = blockIdx.x * 32, by = blockIdx.y * 32;
  int x = bx + threadIdx.x;
  for (int dy = threadIdx.y; dy < 32; dy += 8)
    tile[dy][threadIdx.x] = in[po + (size_t)(by + dy) * N + x];
  __syncthreads();
  int xo = by + threadIdx.x;
  for (int dy = threadIdx.y; dy < 32; dy += 8)
    out[po + (size_t)(bx + dy) * N + xo] = tile[threadIdx.x][dy];
}

// ---------------- pointwise / reduction kernels ----------------
__global__ void lod_only_k(cplx* lod, const cplx* spec, int logN) {
  int N = 1 << logN, n = N * N;
  GS_FOR(idx, n) {
    int i = idx >> logN, j = idx & (N - 1);
    float lr, ang;
    grid_lr_ang(i, j, N, &lr, &ang);
    float l0 = rc_lo_f(lr, -1.0f, 0.0f);
    cplx z = spec[idx];
    lod[idx] = make_float2(z.x * l0, z.y * l0);
  }
}
// slots 4 (sum|rhp|), 5 (sum rhp^2)
__global__ void rhp_stats_k(const cplx* src, int n, double* part) {
  double sa = 0, sq = 0;
  GS_FOR(i, n) {
    float v = src[i].x;
    sa += fabsf(v);
    sq += (double)v * (double)v;
  }
  double v[2] = {sa, sq};
  block_to_parts<2>(part, 4, v);
}
template<int P>
__global__ void extract_band_k(float* realc, float* mag, const cplx* src, int logPer,
                               double* part, int slotBase) {
  int n = (1 << logPer) * P;
  double s0 = 0, s1 = 0, s2 = 0, s3 = 0;
  GS_FOR(idx, n) {
    cplx z = src[idx];
    float m = sqrtf(z.x * z.x + z.y * z.y);
    realc[idx] = z.x;
    mag[idx] = m;       // RAW magnitude (centering folded into assemble-side algebra)
    int p = idx >> logPer;
    if (p == 0) s0 += m; else if (p == 1) s1 += m; else if (p == 2) s2 += m; else s3 += m;
  }
  double v[4] = {s0, s1, s2, s3};
  block_to_parts<P>(part, slotBase, v);
}
__global__ void lod_down_k(cplx* child, const cplx* par, int logNc) {
  int Nc = 1 << logNc, n = Nc * Nc, Np = Nc << 1;
  GS_FOR(idx, n) {
    int i = idx >> logNc, j = idx & (Nc - 1);
    int pi = (i < (Nc >> 1)) ? i : i + Nc;
    int pj = (j < (Nc >> 1)) ? j : j + Nc;
    float lr, ang;
    grid_lr_ang(i, j, Nc, &lr, &ang);
    float l0 = rc_lo_f(lr, -1.0f, 0.0f);
    cplx z = par[pi * Np + pj];
    child[idx] = make_float2(z.x * l0, z.y * l0);
  }
}
__global__ void sum_real2_k(const cplx* src, int n, double* part) {  // slot 24
  double s = 0;
  GS_FOR(i, n) s += (double)src[i].x;
  double v[1] = {s};
  block_to_parts<1>(part, 24, v);
}
__global__ void center_abs2_k(const cplx* src, int n, const double* acc, double* part) {  // slot 25
  float mu = (float)(acc[24] / (double)n);
  double s = 0;
  GS_FOR(i, n) s += fabsf(src[i].x - mu);
  double v[1] = {s};
  block_to_parts<1>(part, 25, v);
}
__global__ void rs4_init_k(cplx* rs, const cplx* lod4) {
  GS_FOR(idx, 4096) {
    int i = idx >> 6, j = idx & 63;
    float lr, ang;
    grid_lr_ang(i, j, 64, &lr, &ang);
    float l0 = rc_lo_f(lr, -1.0f, 0.0f);
    cplx v = lod4[idx];
    if (idx == 0) v = make_float2(0.0f, 0.0f);
    rs[idx] = make_float2(v.x * l0, v.y * l0);
  }
}
__global__ void embed_rs_k(cplx* dst, const cplx* src, int logNb, int zeroDC) {
  int Nb = 1 << logNb, Nc = Nb >> 1, q = Nc >> 1, n = Nb * Nb;
  GS_FOR(idx, n) {
    int i = idx >> logNb, j = idx & (Nb - 1);
    int ci = (i < q) ? i : ((i >= Nb - q) ? (i - Nb + Nc) : -1);
    int cj = (j < q) ? j : ((j >= Nb - q) ? (j - Nb + Nc) : -1);
    cplx v = make_float2(0.0f, 0.0f);
    if (ci >= 0 && cj >= 0) {
      v = src[ci * Nc + cj];
      if (zeroDC && ci == 0 && cj == 0) v = make_float2(0.0f, 0.0f);
    }
    dst[idx] = v;
  }
}
// fused: dst = embed(src into 2x grid) + recon-band spectrum from lod (canonical)
__global__ void recon_step_k(cplx* __restrict__ dst, const cplx* __restrict__ src,
                             const cplx* __restrict__ lod, int logNb) {
  int Nb = 1 << logNb, Nc = Nb >> 1, qq = Nc >> 1, n = Nb * Nb;
  GS_FOR(idx, n) {
    int i = idx >> logNb, j = idx & (Nb - 1);
    int ci = (i < qq) ? i : ((i >= Nb - qq) ? (i - Nb + Nc) : -1);
    int cj = (j < qq) ? j : ((j >= Nb - qq) ? (j - Nb + Nc) : -1);
    float ex = 0.0f, ey = 0.0f;
    if (ci >= 0 && cj >= 0) { cplx v = src[ci * Nc + cj]; ex = v.x; ey = v.y; }
    int ni = (Nb - i) & (Nb - 1), nj = (Nb - j) & (Nb - 1);
    float lr, ang;
    grid_lr_ang(i, j, Nb, &lr, &ang);
    float him = rc_hi_f(lr, -2.0f, -1.0f);
    float l0 = rc_lo_f(lr, -1.0f, 0.0f);
    cplx L = lod[idx];
    cplx L2 = lod[ni * Nb + nj];
    float sx = 0.0f, sy = 0.0f;
#pragma unroll
    for (int b = 0; b < 4; ++b) {
      float c1 = him * amask_c(ang, b);
      float c2 = him * amask_c(ang + PI_F, b);
      float mr = him * amask_r(ang, b);
      float gx = L.x * c1 - L2.x * c2;
      float gy = L.y * c1 + L2.y * c2;
      sx += 0.5f * mr * gx;
      sy += 0.5f * mr * gy;
    }
    dst[idx] = make_float2(ex + sx * l0, ey + sy * l0);
  }
}
// ---- vectorized spatial autocorrelation core (fields stored TRANSPOSED; fixed in assemble) ----
template<int ST, bool SK>
__device__ __forceinline__ void ac_core(const float* __restrict__ xp, int logN,
                                        double* __restrict__ part, int slotBase) {
  const int N = 1 << logN;
  const int nu = (N * N) >> 3;
  float acc[41];
#pragma unroll
  for (int q = 0; q < 41; ++q) acc[q] = 0.0f;
  float a3 = 0.0f, a4 = 0.0f;
  for (int u = blockIdx.x * blockDim.x + threadIdx.x; u < nu; u += gridDim.x * blockDim.x) {
    int i = u >> (logN - 3);
    int j0 = (u & ((N >> 3) - 1)) << 3;
    float buf[5][16];
#pragma unroll
    for (int di = 0; di < 5; ++di) {
      int r = ((i + di) & (N - 1)) << logN;
#pragma unroll
      for (int blk = 0; blk < 4; ++blk) {
        int c = (j0 - 4 + blk * 4) & (N - 1);   // 4-aligned, never straddles wrap
        if (ST == 1) {
          const float4 v = *reinterpret_cast<const float4*>(xp + r + c);
          buf[di][blk * 4 + 0] = v.x; buf[di][blk * 4 + 1] = v.y;
          buf[di][blk * 4 + 2] = v.z; buf[di][blk * 4 + 3] = v.w;
        } else {
          const float4 v0 = *reinterpret_cast<const float4*>(xp + ((size_t)(r + c) << 1));
          const float4 v1 = *reinterpret_cast<const float4*>(xp + ((size_t)(r + c) << 1) + 4);
          buf[di][blk * 4 + 0] = v0.x; buf[di][blk * 4 + 1] = v0.z;
          buf[di][blk * 4 + 2] = v1.x; buf[di][blk * 4 + 3] = v1.z;
        }
      }
    }
#pragma unroll
    for (int k = 0; k < 8; ++k) {
      float xc = buf[0][4 + k];
      if (SK) {
        float x2 = xc * xc;
        a3 += x2 * xc;
        a4 += x2 * x2;
      }
#pragma unroll
      for (int q = 0; q < 41; ++q) {
        const int di = (q < 5) ? 0 : 1 + (q - 5) / 9;
        const int dj = (q < 5) ? q : ((q - 5) % 9) - 4;
        acc[q] += xc * buf[di][4 + k + dj];
      }
    }
  }
  constexpr int NS = SK ? 43 : 41;
  double v[NS];
#pragma unroll
  for (int q = 0; q < 41; ++q) v[q] = (double)acc[q];
  if (SK) { v[41] = (double)a3; v[42] = (double)a4; }
  block_to_parts<NS>(part, slotBase, v);
}
__global__ __launch_bounds__(256) void acm_vec_k(const float* m0, const float* m1,
                                                 const float* m2, const float* m3, double* part) {
  const int s = blockIdx.z;
  const float* base = (s == 0) ? m0 : ((s == 1) ? m1 : ((s == 2) ? m2 : m3));
  const int logN = 10 - s;
  const float* xp = base + ((size_t)blockIdx.y << (2 * logN));
  ac_core<1, false>(xp, logN, part, 448 + (s * 4 + blockIdx.y) * 41);
}
__global__ __launch_bounds__(256) void ac_rec_k(const float* x, int logN, double* part, int slotBase) {
  ac_core<2, true>(x, logN, part, slotBase);
}
// one-pass image stats: raw moments S1..S4 (slots 0..3) + min/max
__global__ void img_stats_k(const float* img, int n, double* part, float* mm) {
  double s1 = 0, s2 = 0, s3 = 0, s4 = 0;
  float mn = INFINITY, mx = -INFINITY;
  GS_FOR(i, n) {
    float vf = img[i];
    double v = (double)vf, v2 = v * v;
    s1 += v; s2 += v2; s3 += v2 * v; s4 += v2 * v2;
    mn = fminf(mn, vf);
    mx = fmaxf(mx, vf);
  }
  double v[4] = {s1, s2, s3, s4};
  block_to_parts<4>(part, 0, v);
#pragma unroll
  for (int o = 32; o > 0; o >>= 1) {
    mn = fminf(mn, __shfl_down(mn, o));
    mx = fmaxf(mx, __shfl_down(mx, o));
  }
  if ((threadIdx.x & 63) == 0) {
    atomicMinF(mm + 0, mn);
    atomicMaxF(mm + 1, mx);
  }
}
// all 8 gram reductions in one launch: grid (RED_GRID, 8); y = s*2 + isReal
__global__ __launch_bounds__(256) void gram8_k(const float* m0, const float* m1, const float* m2,
                                               const float* m3, const float* r0, const float* r1,
                                               const float* r2, const float* r3, double* part) {
  const int c = blockIdx.y;
  const int s = c >> 1, isReal = c & 1;
  const float* base = isReal ? ((s == 0) ? r0 : ((s == 1) ? r1 : ((s == 2) ? r2 : r3)))
                             : ((s == 0) ? m0 : ((s == 1) ? m1 : ((s == 2) ? m2 : m3)));
  const int n = (1024 >> s) * (1024 >> s);
  double g[16];
  double ss[4];
#pragma unroll
  for (int q = 0; q < 16; ++q) g[q] = 0;
#pragma unroll
  for (int q = 0; q < 4; ++q) ss[q] = 0;
  GS_FOR(i, n) {
    double d0 = base[i], d1 = base[n + i], d2 = base[2 * n + i], d3 = base[3 * n + i];
    g[0] += d0 * d0; g[1] += d0 * d1; g[2]  += d0 * d2; g[3]  += d0 * d3;
    g[5] += d1 * d1; g[6] += d1 * d2; g[7]  += d1 * d3;
    g[10] += d2 * d2; g[11] += d2 * d3;
    g[15] += d3 * d3;
    if (!isReal) { ss[0] += d0; ss[1] += d1; ss[2] += d2; ss[3] += d3; }
  }
  g[4] = g[1]; g[8] = g[2]; g[12] = g[3]; g[9] = g[6]; g[13] = g[7]; g[14] = g[11];
  if (isReal) {
    double v[16];
#pragma unroll
    for (int q = 0; q < 16; ++q) v[q] = g[q];
    block_to_parts<16>(part, 144 + s * 16, v);
  } else {
    double v[20];
#pragma unroll
    for (int q = 0; q < 16; ++q) v[q] = g[q];
#pragma unroll
    for (int q = 0; q < 4; ++q) v[16 + q] = ss[q];
    block_to_parts<20>(part, 64 + s * 20, v);
  }
}
// parent reduce, batched over planes via blockIdx.y
__global__ void parent_reduce_k(const cplx* parBase, const float* magS, const float* realS, int n,
                                double* part, int slotBase0) {
  const int pl = blockIdx.y;
  const cplx* par = parBase + (size_t)pl * n;
  double d[13];
#pragma unroll
  for (int q = 0; q < 13; ++q) d[q] = 0;
  GS_FOR(i, n) {
    cplx z = par[i];
    float rt = z.x, it = z.y;
    float mg = sqrtf(rt * rt + it * it);
    float rpr = 0.0f, rpi = 0.0f;
    if (mg > 0.0f) {
      rpr = (it * it - rt * rt) / mg;
      rpi = 2.0f * rt * it / mg;
    }
    d[0] += (double)mg;
#pragma unroll
    for (int b = 0; b < 4; ++b) d[1 + b] += (double)magS[b * n + i] * (double)mg;
#pragma unroll
    for (int b = 0; b < 4; ++b) {
      double rv = (double)realS[b * n + i];
      d[5 + b] += rv * (double)rpr;
      d[9 + b] += rv * (double)rpi;
    }
  }
  block_to_parts<13>(part, slotBase0 + pl * 13, d);
}
// lowpass parents on TRANSPOSED X: rolls on stored axes match reference's tmp=X.T directly
__global__ void lp_parent2_k(const cplx* X, const float* realS, int logN, double* part) {  // slots 370..414
  int N = 1 << logN, n = N * N;
  double d[45];
#pragma unroll
  for (int q = 0; q < 45; ++q) d[q] = 0;
  GS_FOR(idx, n) {
    int i = idx >> logN, j = idx & (N - 1);
    float c[5];
    c[0] = X[idx].x;
    c[1] = X[((i - 1) & (N - 1)) * N + j].x;   // roll +1 axis0 (stored)
    c[2] = X[((i + 1) & (N - 1)) * N + j].x;   // roll -1 axis0
    c[3] = X[i * N + ((j - 1) & (N - 1))].x;   // roll +1 axis1
    c[4] = X[i * N + ((j + 1) & (N - 1))].x;   // roll -1 axis1
#pragma unroll
    for (int b = 0; b < 4; ++b) {
      double rv = (double)realS[b * n + idx];
#pragma unroll
      for (int k = 0; k < 5; ++k) d[b * 5 + k] += rv * (double)c[k];
    }
#pragma unroll
    for (int a = 0; a < 5; ++a)
#pragma unroll
      for (int k = 0; k < 5; ++k) d[20 + a * 5 + k] += (double)c[a] * (double)c[k];
  }
  block_to_parts<45>(part, 370, d);
}
__global__ void init_mm_k(float* mm) {
  if (threadIdx.x == 0) { mm[0] = INFINITY; mm[1] = -INFINITY; }
}

// ---------------- final assembly ----------------
// MAG is RAW; centering corrections done here in f64:
//   acm centered ac(d) = raw_ac(d) - n*m^2 ; coc_mag C_ij = G_ij/n - m_i*m_j ;
//   csc_mag identity (D - meanp*Sc)/n is exact for raw inputs. Image moments via binomial.
__global__ void assemble_k(float* out, const double* acc, const float* mm) {
  const int t = threadIdx.x;
  const double NPIX = 1048576.0;
  const double muI = acc[0] / NPIX;
  const double var0 = (acc[1] - NPIX * muI * muI) / (NPIX - 1.0);
  if (t == 0) {
    out[0] = (float)muI;
    out[1] = (float)var0;
    double m3c = (acc[2] - 3.0 * muI * acc[1] + 2.0 * NPIX * muI * muI * muI) / NPIX;
    double m4c = (acc[3] - 4.0 * muI * acc[2] + 6.0 * muI * muI * acc[1]
                  - 3.0 * NPIX * muI * muI * muI * muI) / NPIX;
    out[2] = (float)(m3c / pow(var0, 1.5));
    out[3] = (float)(m4c / (var0 * var0));
    out[4] = mm[0];
    out[5] = mm[1];
    out[2455] = (float)(acc[5] / NPIX);  // var_hp
  }
  for (int k = t; k < 18; k += blockDim.x) {  // mag_means (raw sums)
    double n, sv;
    if (k == 0) { n = NPIX; sv = acc[4]; }
    else if (k == 17) { n = 4096.0; sv = acc[25]; }
    else { int s = (k - 1) >> 2; double dd = (double)(1024 >> s); n = dd * dd; sv = acc[7 + k]; }
    out[6 + k] = (float)(sv / n);
  }
  for (int si = t; si < 5; si += blockDim.x) {  // skew_r / kurt_r
    double dd = (si == 4) ? 64.0 : (double)(1024 >> si);
    double nn = dd * dd;
    double vari = acc[1104 + si * 43] / nn;
    bool cond = (vari / var0) > 1e-6;
    double m3 = acc[1104 + si * 43 + 41] / nn, m4 = acc[1104 + si * 43 + 42] / nn;
    out[1320 + si] = (float)(cond ? m3 / pow(vari, 1.5) : 0.0);
    out[1325 + si] = (float)(cond ? m4 / (vari * vari) : 3.0);
  }
  for (int w = t; w < 656; w += blockDim.x) {  // acm: raw ac - m^2, transposed di/dj swap
    int patch = w / 41, q = w - patch * 41;
    int s = patch >> 2, b = patch & 3;
    double dd = (double)(1024 >> s);
    double nn = dd * dd;
    double mb = acc[8 + s * 4 + b] / nn;
    double v = acc[448 + w] / nn - mb * mb;
    int di = (q < 5) ? 0 : 1 + (q - 5) / 9;
    int dj = (q < 5) ? q : ((q - 5) % 9) - 4;
    int pi = 4 + dj, pj = 4 + di;        // SWAPPED for transposed storage
    out[24 + 144 * pi + 16 * pj + 4 * s + b] = (float)v;
    if (q) out[24 + 144 * (8 - pi) + 16 * (8 - pj) + 4 * s + b] = (float)v;
  }
  for (int w = t; w < 205; w += blockDim.x) {  // auto_corr (recon raw; transposed swap)
    int si = w / 41, q = w - si * 41;
    double dd = (si == 4) ? 64.0 : (double)(1024 >> si);
    double v = acc[1104 + si * 43 + q] / (dd * dd);
    int di = (q < 5) ? 0 : 1 + (q - 5) / 9;
    int dj = (q < 5) ? q : ((q - 5) % 9) - 4;
    int pi = 4 + dj, pj = 4 + di;        // SWAPPED
    out[1330 + (pi * 9 + pj) * 5 + si] = (float)v;
    if (q) out[1330 + ((8 - pi) * 9 + (8 - pj)) * 5 + si] = (float)v;
  }
  for (int q = t; q < 64; q += blockDim.x) {  // coc_mag: G/n - mi*mj
    int s = q >> 4, ij = q & 15;
    double dd = (double)(1024 >> s); double csz = dd * dd;
    double mi = acc[8 + s * 4 + (ij >> 2)] / csz;
    double mj = acc[8 + s * 4 + (ij & 3)] / csz;
    out[1735 + ij * 5 + s] = (float)(acc[64 + s * 20 + ij] / csz - mi * mj);
  }
  for (int q = t; q < 64; q += blockDim.x) {  // coc_real s=0..3 (realc raw in reference)
    int s = q >> 4, ij = q & 15;
    int i = ij >> 2, j = ij & 3;
    double dd = (double)(1024 >> s); double csz = dd * dd;
    out[1879 + (i * 8 + j) * 5 + s] = (float)(acc[144 + s * 16 + ij] / csz);
  }
  for (int q = t; q < 25; q += blockDim.x) {  // coc_real s=4
    int a = q / 5, b2 = q - a * 5;
    out[1879 + (a * 8 + b2) * 5 + 4] = (float)(acc[390 + q] / 4096.0);
  }
  for (int q = t; q < 48; q += blockDim.x) {  // csc_mag s=0..2 (identity exact with raw sums)
    int s = q >> 4, ij = q & 15;
    int i = ij >> 2, pb = ij & 3;
    double dd = (double)(1024 >> s); double csz = dd * dd;
    const double* ps = acc + 208 + (s * 4 + pb) * 13;
    double meanp = ps[0] / csz;
    double cousSum = acc[64 + s * 20 + 16 + i];
    out[1815 + (i * 4 + pb) * 4 + s] = (float)((ps[1 + i] - meanp * cousSum) / csz);
  }
  for (int q = t; q < 96; q += blockDim.x) {  // csc_real s=0..2
    int s = q >> 5, r = q & 31;
    int i = r >> 3, j = r & 7;
    int pb = j & 3, offq = (j >= 4) ? 9 : 5;
    double dd = (double)(1024 >> s); double csz = dd * dd;
    out[2199 + (i * 8 + j) * 4 + s] = (float)(acc[208 + (s * 4 + pb) * 13 + offq + i] / csz);
  }
  for (int q = t; q < 20; q += blockDim.x) {  // csc_real s=3
    int i = q / 5, c = q - i * 5;
    out[2199 + (i * 8 + c) * 4 + 3] = (float)(acc[370 + q] / 16384.0);
  }
}

// ---------------- host-side FFT dispatch ----------------
static inline int thr_for(int N) { return (N >= 512) ? 256 : ((N == 256) ? 128 : 64); }
template<int MODE>
static void fft_pass(int N, int rows, bool inv, cplx* dst, const void* src, const cplx* aux,
                     int b0, hipStream_t st) {
  dim3 g(rows), b(thr_for(N));
  switch (N) {
    case 64:
      if (inv) fftm_k<6, true, MODE><<<g, b, 0, st>>>(dst, src, aux, b0);
      else     fftm_k<6, false, MODE><<<g, b, 0, st>>>(dst, src, aux, b0);
      break;
    case 128:
      if (inv) fftm_k<7, true, MODE><<<g, b, 0, st>>>(dst, src, aux, b0);
      else     fftm_k<7, false, MODE><<<g, b, 0, st>>>(dst, src, aux, b0);
      break;
    case 256:
      if (inv) fftm_k<8, true, MODE><<<g, b, 0, st>>>(dst, src, aux, b0);
      else     fftm_k<8, false, MODE><<<g, b, 0, st>>>(dst, src, aux, b0);
      break;
    case 512:
      if (inv) fftm_k<9, true, MODE><<<g, b, 0, st>>>(dst, src, aux, b0);
      else     fftm_k<9, false, MODE><<<g, b, 0, st>>>(dst, src, aux, b0);
      break;
    case 1024:
      if (inv) fftm_k<10, true, MODE><<<g, b, 0, st>>>(dst, src, aux, b0);
      else     fftm_k<10, false, MODE><<<g, b, 0, st>>>(dst, src, aux, b0);
      break;
    default: break;
  }
}
static void transp(cplx* out, const cplx* in, int N, int P, hipStream_t st) {
  dim3 tg(N / 32, N / 32, P), tb(32, 8);
  transpose_k<<<tg, tb, 0, st>>>(out, in, N);
}
// ifft2 producing TRANSPOSED spatial output in `out`
template<int MODE>
static void ifft2dT(int N, int P, cplx* out, cplx* tmp, const void* src, const cplx* aux,
                    int b0, hipStream_t st) {
  fft_pass<MODE>(N, N * P, true, tmp, src, aux, b0, st);
  transp(out, tmp, N, P, st);
  fft_pass<MD_PLAIN>(N, N * P, true, out, out, nullptr, 0, st);
}
static inline dim3 gsz(int n) {
  int b = (n + 255) >> 8;
  if (b > 2048) b = 2048;
  if (b < 1) b = 1;
  return dim3(b);
}

extern "C" void kernel_launch(void* const* d_in, const int* in_sizes, int n_in,
                              void* d_out, int out_size, void* d_ws, size_t ws_size,
                              hipStream_t stream) {
  (void)in_sizes; (void)n_in; (void)out_size; (void)ws_size;
  const float* img = (const float*)d_in[0];
  float* out = (float*)d_out;

  char* wsb = (char*)d_ws;
  size_t off = 0;
  auto alloc = [&](size_t bytes) -> void* {
    void* p = wsb + off;
    off += (bytes + 255) & ~(size_t)255;
    return p;
  };
  const size_t MB = (size_t)1 << 20;
  const int NSLOT = 1320;
  cplx* cA = (cplx*)alloc(16 * MB);
  cplx* cB = (cplx*)alloc(16 * MB);
  cplx* LOD[5];
  for (int s = 0; s < 5; ++s) {
    int N = 1024 >> s;
    LOD[s] = (cplx*)alloc((size_t)N * N * sizeof(cplx));
  }
  cplx* RS[4];
  for (int k = 0; k < 4; ++k) {
    int N = 64 << k;
    RS[k] = (cplx*)alloc((size_t)N * N * sizeof(cplx));
  }
  float* MAG[4];
  float* REALC[4];
  for (int s = 0; s < 4; ++s) {
    int N = 1024 >> s;
    MAG[s] = (float*)alloc((size_t)4 * N * N * sizeof(float));
  }
  for (int s = 0; s < 4; ++s) {
    int N = 1024 >> s;
    REALC[s] = (float*)alloc((size_t)4 * N * N * sizeof(float));
  }
  const int NPIX = 1024 * 1024;
  double* PART = (double*)alloc((size_t)NSLOT * RED_GRID * 8);
  double* ACC  = (double*)alloc(2048 * 8);
  float* MM    = (float*)alloc(256);

  auto finish = [&](int base, int count) {
    reduce_parts_k<<<dim3(count), 64, 0, stream>>>(ACC, PART, base);
  };

  hipMemsetAsync(out, 0, 2456 * sizeof(float), stream);
  init_mm_k<<<1, 64, 0, stream>>>(MM);

  // ---- Phase A: pixel stats (one pass, raw moments) ----
  img_stats_k<<<dim3(RED_GRID), 256, 0, stream>>>(img, NPIX, PART, MM);

  // ---- Phase B: forward FFT (canonical spectrum in cA) ----
  fft_pass<MD_R2C>(1024, 1024, false, cA, img, nullptr, 0, stream);
  transp(cB, cA, 1024, 1, stream);
  fft_pass<MD_PLAIN>(1024, 1024, false, cB, cB, nullptr, 0, stream);
  transp(cA, cB, 1024, 1, stream);
  lod_only_k<<<gsz(NPIX), 256, 0, stream>>>(LOD[0], cA, 10);
  ifft2dT<MD_HP>(1024, 1, cA, cB, cA, nullptr, 0, stream);
  rhp_stats_k<<<dim3(RED_GRID), 256, 0, stream>>>(cA, NPIX, PART);
  for (int b0 = 0; b0 < 4; b0 += 2) {  // s=0 bands
    ifft2dT<MD_BAND>(1024, 2, cB, cA, nullptr, LOD[0], b0, stream);
    extract_band_k<2><<<dim3(RED_GRID), 256, 0, stream>>>(REALC[0] + (size_t)b0 * NPIX,
                                                          MAG[0] + (size_t)b0 * NPIX, cB, 20, PART, 8 + b0);
  }
  lod_down_k<<<gsz(512 * 512), 256, 0, stream>>>(LOD[1], LOD[0], 9);
  for (int s = 1; s <= 3; ++s) {
    int N = 1024 >> s, logN = 10 - s;
    ifft2dT<MD_BAND>(N, 4, cB, cA, nullptr, LOD[s], 0, stream);
    extract_band_k<4><<<dim3(RED_GRID), 256, 0, stream>>>(REALC[s], MAG[s], cB, 2 * logN, PART, 8 + 4 * s);
    lod_down_k<<<gsz((N / 2) * (N / 2)), 256, 0, stream>>>(LOD[s + 1], LOD[s], logN - 1);
  }
  // residual lowpass spatial stats (LOD[4] preserved)
  ifft2dT<MD_PLAIN>(64, 1, cB, cA, LOD[4], nullptr, 0, stream);
  sum_real2_k<<<dim3(RED_GRID), 256, 0, stream>>>(cB, 4096, PART);
  finish(24, 1);
  center_abs2_k<<<dim3(RED_GRID), 256, 0, stream>>>(cB, 4096, ACC, PART);

  // ---- acm: all 16 raw autocorrs, one launch ----
  acm_vec_k<<<dim3(RED_GRID, 4, 4), 256, 0, stream>>>(MAG[0], MAG[1], MAG[2], MAG[3], PART);

  // ---- Phase C: recon chain ----
  rs4_init_k<<<gsz(4096), 256, 0, stream>>>(RS[0], LOD[4]);
  ifft2dT<MD_PLAIN>(64, 1, cB, cA, RS[0], nullptr, 0, stream);
  ac_rec_k<<<dim3(RED_GRID), 256, 0, stream>>>((const float*)cB, 6, PART, 1104 + 4 * 43);
  cplx* cur = RS[0];
  for (int s = 3; s >= 0; --s) {
    int N = 1024 >> s, logN = 10 - s, n = N * N;
    cplx* sp = (s > 0) ? RS[4 - s] : cB;
    recon_step_k<<<gsz(n), 256, 0, stream>>>(sp, cur, LOD[s], logN);
    ifft2dT<MD_PLAIN>(N, 1, cB, cA, sp, nullptr, 0, stream);
    ac_rec_k<<<dim3(RED_GRID), 256, 0, stream>>>((const float*)cB, logN, PART, 1104 + s * 43);
    cur = sp;
  }

  // ---- Phase D: cross-correlations ----
  gram8_k<<<dim3(RED_GRID, 8), 256, 0, stream>>>(MAG[0], MAG[1], MAG[2], MAG[3],
                                                 REALC[0], REALC[1], REALC[2], REALC[3], PART);
  // s=0 parents: EMB-fused ifft from LOD[1], 2-plane batches; batched reduce
  for (int pb0 = 0; pb0 < 4; pb0 += 2) {
    ifft2dT<MD_EMB>(1024, 2, cB, cA, nullptr, LOD[1], pb0, stream);
    parent_reduce_k<<<dim3(RED_GRID, 2), 256, 0, stream>>>(cB, MAG[0], REALC[0], NPIX,
                                                           PART, 208 + pb0 * 13);
  }
  // s=1,2 parents: EMB-fused ifft, 4-plane batch; batched reduce
  for (int s = 1; s <= 2; ++s) {
    int N = 1024 >> s, n = N * N;
    ifft2dT<MD_EMB>(N, 4, cB, cA, nullptr, LOD[s + 1], 0, stream);
    parent_reduce_k<<<dim3(RED_GRID, 4), 256, 0, stream>>>(cB, MAG[s], REALC[s], n,
                                                           PART, 208 + s * 4 * 13);
  }
  // s=3: expanded (centered) lowpass + rolls (transposed; rolls handled in lp_parent2_k)
  embed_rs_k<<<gsz(128 * 128), 256, 0, stream>>>(cA, LOD[4], 7, 1);
  ifft2dT<MD_PLAIN>(128, 1, cB, cA + 16384, cA, nullptr, 0, stream);
  lp_parent2_k<<<dim3(RED_GRID), 256, 0, stream>>>(cB, REALC[3], 7, PART);

  finish(0, NSLOT);
  assemble_k<<<1, 256, 0, stream>>>(out, ACC, MM);
}